// Round 3
// baseline (1432.627 us; speedup 1.0000x reference)
//
#include <hip/hip_runtime.h>

// ---------------------------------------------------------------------------
// SparseKT forward, MI355X gfx950. I/O dtype: fp32 (per reference).
// Numerics: fp32 tensors decomposed into hi/lo bf16 pairs (pseudo-fp32,
// rel err ~2^-17). GEMMs are split-3: C = Ah*Bh + Ah*Bl + Al*Bh (3 MFMAs).
// Softmax / exact top-5 / LayerNorm in fp32. Residual stream: hi/lo pairs.
// R7->R8: R7's attn rewrite (bitonic top-5 + lockstep + depth-2 prefetch)
// FAILED absmax (0.297 > 0.116); attn reverted byte-exact to the R6 passing
// version. This round, numerics-neutral only:
//   (a) y = ie + pos precomputed to bf16 hi/lo (init_x_kernel reuse, identical
//       split), v-GEMM switched to the global_load_lds fast path (flags=8):
//       halves v-GEMM staging bytes, removes its in-kernel split VALU.
//       Output V^T is bit-identical. ws_size-guarded fallback to flag-4 path.
//   (b) s_setprio(1) around attn MFMA clusters (runtime hint, numerics-free).
// ---------------------------------------------------------------------------

#define L_   2
#define B_   32
#define S_   512
#define D_   512
#define H_   8
#define DH_  64
#define DFF_ 2048
#define BS_  (B_*S_)      // 16384

typedef __bf16 bfx8 __attribute__((ext_vector_type(8)));
typedef __bf16 bfx4 __attribute__((ext_vector_type(4)));
typedef float floatx4 __attribute__((ext_vector_type(4)));

__device__ __forceinline__ floatx4 mfma_bf16(bfx8 a, bfx8 b, floatx4 c) {
  return __builtin_amdgcn_mfma_f32_16x16x32_bf16(a, b, c, 0, 0, 0);
}

__device__ __forceinline__ float wave_sum(float v) {
  #pragma unroll
  for (int d = 32; d > 0; d >>= 1) v += __shfl_xor(v, d);
  return v;
}
__device__ __forceinline__ float wave_max(float v) {
  #pragma unroll
  for (int d = 32; d > 0; d >>= 1) v = fmaxf(v, __shfl_xor(v, d));
  return v;
}

// async global->LDS, 16 B per lane; LDS dest = wave-uniform base + lane*16
__device__ __forceinline__ void lds_load16(__bf16* lds, const __bf16* g) {
  __builtin_amdgcn_global_load_lds(
      (const __attribute__((address_space(1))) unsigned int*)g,
      (__attribute__((address_space(3))) unsigned int*)lds, 16, 0, 0);
}

// LDS chunk swizzle: logical 8-elem chunk q of row r stored at q ^ ((r>>1)&3)
__device__ __forceinline__ int swz(int row, int q) { return q ^ ((row >> 1) & 3); }

// ---------------------------------------------------------------------------
// init: x = emb + pos (fp32) -> bf16 hi/lo pair (used for both qe and ie)
// ---------------------------------------------------------------------------
__global__ void init_x_kernel(const float* __restrict__ qe, const float* __restrict__ pos,
                              __bf16* __restrict__ xh, __bf16* __restrict__ xl)
{
  size_t i = ((size_t)blockIdx.x * 256 + threadIdx.x) * 8;
  float4 a0 = *(const float4*)(qe + i);
  float4 a1 = *(const float4*)(qe + i + 4);
  size_t pi = i & (size_t)(S_*D_ - 1);
  float4 p0 = *(const float4*)(pos + pi);
  float4 p1 = *(const float4*)(pos + pi + 4);
  float v[8] = {a0.x+p0.x, a0.y+p0.y, a0.z+p0.z, a0.w+p0.w,
                a1.x+p1.x, a1.y+p1.y, a1.z+p1.z, a1.w+p1.w};
  bfx8 hv8, lv8;
  #pragma unroll
  for (int j = 0; j < 8; ++j) {
    __bf16 hv = (__bf16)v[j];
    hv8[j] = hv;
    lv8[j] = (__bf16)(v[j] - (float)hv);
  }
  *(bfx8*)(xh + i) = hv8;
  *(bfx8*)(xl + i) = lv8;
}

// ---------------------------------------------------------------------------
// weight transpose + hi/lo split:  W[K][N] fp32  ->  T{h,l}[N][K] bf16
// ---------------------------------------------------------------------------
__global__ void transpose_split_kernel(const float* __restrict__ Wsrc,
                                       __bf16* __restrict__ Th, __bf16* __restrict__ Tl,
                                       int K, int N)
{
  __shared__ float tile[32][33];
  int n0 = blockIdx.x * 32, k0 = blockIdx.y * 32;
  int tx = threadIdx.x & 31, ty8 = threadIdx.x >> 5;  // 0..7
  #pragma unroll
  for (int j = 0; j < 4; ++j) {
    int k = ty8 + j*8;
    tile[k][tx] = Wsrc[(size_t)(k0 + k) * N + n0 + tx];
  }
  __syncthreads();
  #pragma unroll
  for (int j = 0; j < 4; ++j) {
    int n = ty8 + j*8;
    float vv = tile[tx][n];           // = W[k0+tx][n0+n]
    size_t dst = (size_t)(n0 + n) * K + k0 + tx;
    __bf16 hv = (__bf16)vv;
    Th[dst] = hv;
    Tl[dst] = (__bf16)(vv - (float)hv);
  }
}

// ---------------------------------------------------------------------------
// split-3 GEMM: C[M,N] = A[M,K] @ Bt[N,K]^T + bias; output bf16 hi/lo pair.
// flags: 1 = relu, 4 = stage A from fp32 (Afa[m] + Afp[m mod S]) on the fly
//        8 = write transposed per-batch output C^T[b][n][s] (b = m/S, s = m%S)
// 128x128x32 tile, 4 waves (64x64 quadrant each, 16 MFMA tiles).
// Fast path (no flag 4): wave w DMA-stages buffer w via global_load_lds x8.
// LDS XOR-swizzled (swz) -> conflict-free ds_read_b128 fragments, no padding.
// ---------------------------------------------------------------------------
__global__ __launch_bounds__(256, 2)
void gemm_split3_kernel(const __bf16* __restrict__ Ah, const __bf16* __restrict__ Al,
                        const float* __restrict__ Afa, const float* __restrict__ Afp,
                        const __bf16* __restrict__ Bth, const __bf16* __restrict__ Btl,
                        const float* __restrict__ bias,
                        __bf16* __restrict__ Ch, __bf16* __restrict__ Cl,
                        int M, int N, int K, int flags)
{
  __shared__ __bf16 sAh[128*32], sAl[128*32], sBh[128*32], sBl[128*32];
  const int t = threadIdx.x;
  const int w = t >> 6, lane = t & 63;
  const int q4 = lane >> 4, r16 = lane & 15;
  const int m0 = blockIdx.y * 128, n0 = blockIdx.x * 128;
  const int wm = (w >> 1) * 64, wn = (w & 1) * 64;

  floatx4 acc[4][4];
  #pragma unroll
  for (int i = 0; i < 4; ++i)
    #pragma unroll
    for (int j = 0; j < 4; ++j)
      acc[i][j] = (floatx4){0.f, 0.f, 0.f, 0.f};

  // fast-path per-wave staging assignment: wave w stages buffer w
  const __bf16* wsrc = (w == 0) ? Ah : (w == 1) ? Al : (w == 2) ? Bth : Btl;
  __bf16* wdst = (w == 0) ? sAh : (w == 1) ? sAl : (w == 2) ? sBh : sBl;
  const int rbase = (w < 2) ? m0 : n0;
  const int rl = lane >> 2;        // row within 16-row group
  const int cp = lane & 3;         // physical chunk this lane fills

  // manual-path (flags&4) mapping
  const int srow = t >> 2;          // 0..63
  const int sq   = t & 3;           // logical chunk

  for (int k0 = 0; k0 < K; k0 += 32) {
    __syncthreads();
    if (!(flags & 4)) {
      #pragma unroll
      for (int g = 0; g < 8; ++g) {
        int row = g*16 + rl;
        int ql = swz(row, cp);       // logical chunk landing at phys cp
        const __bf16* gp = wsrc + (size_t)(rbase + row) * K + k0 + ql*8;
        lds_load16(wdst + g*512, gp);
      }
    } else {
      #pragma unroll
      for (int c = 0; c < 2; ++c) {
        int row = srow + c * 64;
        size_t ga = (size_t)(m0 + row) * K + k0 + sq*8;
        size_t gp = (size_t)((m0 + row) & (S_ - 1)) * K + k0 + sq*8;
        float4 e0 = *(const float4*)&Afa[ga];
        float4 e1 = *(const float4*)&Afa[ga + 4];
        float4 p0 = *(const float4*)&Afp[gp];
        float4 p1 = *(const float4*)&Afp[gp + 4];
        float sv[8] = {e0.x+p0.x, e0.y+p0.y, e0.z+p0.z, e0.w+p0.w,
                       e1.x+p1.x, e1.y+p1.y, e1.z+p1.z, e1.w+p1.w};
        bfx8 hv8, lv8;
        #pragma unroll
        for (int j = 0; j < 8; ++j) {
          __bf16 hv = (__bf16)sv[j];
          hv8[j] = hv;
          lv8[j] = (__bf16)(sv[j] - (float)hv);
        }
        int pc = swz(row, sq);
        *(bfx8*)&sAh[row*32 + pc*8] = hv8;
        *(bfx8*)&sAl[row*32 + pc*8] = lv8;
        size_t gb = (size_t)(n0 + row) * K + k0 + sq*8;
        *(bfx8*)&sBh[row*32 + pc*8] = *(const bfx8*)&Bth[gb];
        *(bfx8*)&sBl[row*32 + pc*8] = *(const bfx8*)&Btl[gb];
      }
    }
    __syncthreads();
    bfx8 af[4][2], bfr[4][2];
    #pragma unroll
    for (int i = 0; i < 4; ++i) {
      int ar = wm + i*16 + r16;
      int sa = swz(ar, q4) * 8;
      af[i][0] = *(const bfx8*)&sAh[ar*32 + sa];
      af[i][1] = *(const bfx8*)&sAl[ar*32 + sa];
      int br = wn + i*16 + r16;
      int sb = swz(br, q4) * 8;
      bfr[i][0] = *(const bfx8*)&sBh[br*32 + sb];
      bfr[i][1] = *(const bfx8*)&sBl[br*32 + sb];
    }
    #pragma unroll
    for (int i = 0; i < 4; ++i)
      #pragma unroll
      for (int j = 0; j < 4; ++j) {
        acc[i][j] = mfma_bf16(af[i][0], bfr[j][0], acc[i][j]);
        acc[i][j] = mfma_bf16(af[i][0], bfr[j][1], acc[i][j]);
        acc[i][j] = mfma_bf16(af[i][1], bfr[j][0], acc[i][j]);
      }
  }

  // epilogue (C/D layout: col = lane&15, row = (lane>>4)*4 + reg  [m89-verified])
  if (flags & 8) {
    // transposed per-batch write: C^T[b][n][s]; 4 regs = 4 consecutive s -> 8B store
    #pragma unroll
    for (int i = 0; i < 4; ++i)
      #pragma unroll
      for (int j = 0; j < 4; ++j) {
        int gn = n0 + wn + j*16 + r16;
        float bb = bias[gn];
        int gmb = m0 + wm + i*16 + q4*4;
        size_t co = ((size_t)(gmb >> 9) * N + gn) * S_ + (gmb & (S_ - 1));
        bfx4 hv4, lv4;
        #pragma unroll
        for (int r = 0; r < 4; ++r) {
          float val = acc[i][j][r] + bb;
          if (flags & 1) val = fmaxf(val, 0.f);
          __bf16 hv = (__bf16)val;
          hv4[r] = hv;
          lv4[r] = (__bf16)(val - (float)hv);
        }
        *(bfx4*)(Ch + co) = hv4;
        *(bfx4*)(Cl + co) = lv4;
      }
  } else {
    #pragma unroll
    for (int i = 0; i < 4; ++i)
      #pragma unroll
      for (int j = 0; j < 4; ++j) {
        int gn = n0 + wn + j*16 + r16;
        float bb = bias[gn];
        #pragma unroll
        for (int r = 0; r < 4; ++r) {
          int gm = m0 + wm + i*16 + q4*4 + r;
          float val = acc[i][j][r] + bb;
          if (flags & 1) val = fmaxf(val, 0.f);
          size_t co = (size_t)gm * N + gn;
          __bf16 hv = (__bf16)val;
          Ch[co] = hv;
          Cl[co] = (__bf16)(val - (float)hv);
        }
      }
  }
}

// ---------------------------------------------------------------------------
// attention: 1-D grid 8192, decoded so batch b == XCD (lin&7): K/V of a batch
// stay L2-resident on one XCD. Heavy q-tiles first within each XCD.
// phase 1: scores via MFMA (split-3), register-prefetched K tiles
// phase 2: softmax + exact top-5 re-softmax, fully static (regs); final P is
//          written back as bf16 hi/lo into the Ssc row footprint
// phase 3: O^T = V^T @ P^T; V^T tiles staged from the pre-transposed global
//          V^T ([b][n][s], produced by the v-GEMM) -> all-vector LDS ops
// (byte-exact R6 structure; only change: s_setprio around MFMA clusters)
// ---------------------------------------------------------------------------
__global__ __launch_bounds__(256, 2)
void attn_kernel(const __bf16* __restrict__ qh, const __bf16* __restrict__ ql,
                 const __bf16* __restrict__ vth, const __bf16* __restrict__ vtl,
                 __bf16* __restrict__ oh, __bf16* __restrict__ ol)
{
  constexpr int LSS = 516;                       // fp32 row stride (pad 4)
  constexpr int LDV = 72;                        // bf16 row stride, 16B-mult
  __shared__ float  Ssc[16*LSS];                 // 33 KB score rows; P hi/lo after phase 2
  __shared__ __bf16 KVh[64*LDV];                 // K tile [key][dh] / V^T tile [dh][key]
  __shared__ __bf16 KVl[64*LDV];
  const int lin = blockIdx.x;
  const int xcd = lin & 7;
  const int ord = lin >> 3;                      // 0..1023 per xcd
  const int qt  = 31 - (ord & 31);               // heavy tiles first
  const int bh  = ord >> 5;                      // 0..31
  const int hd  = bh & 7;
  const int b   = ((bh >> 3) << 3) | xcd;        // b mod 8 == xcd
  const int t = threadIdx.x, w = t >> 6, lane = t & 63;
  const int q4 = lane >> 4, r16 = lane & 15;
  const int nkt = (qt >> 2) + 1;                 // 64-key tiles (causal)

  // Q fragments (A operand): rows qt*16+[0,16), cols hd*64+[0,64)
  bfx8 qf[2][2];
  {
    size_t base = ((size_t)(b*S_ + qt*16 + r16)) * D_ + hd*64;
    #pragma unroll
    for (int ks = 0; ks < 2; ++ks) {
      qf[ks][0] = *(const bfx8*)&qh[base + ks*32 + q4*8];
      qf[ks][1] = *(const bfx8*)&ql[base + ks*32 + q4*8];
    }
  }

  const int srow8 = t >> 3;        // 0..31
  const int scol8 = (t & 7) * 8;   // 0..56

  bfx8 pf_h[2], pf_l[2];           // prefetch registers (K or V^T tile)
  auto loadK = [&](int kt) {
    #pragma unroll
    for (int c = 0; c < 2; ++c) {
      int row = srow8 + c*32;
      size_t src = ((size_t)(b*S_ + kt*64 + row)) * D_ + hd*64 + scol8;
      pf_h[c] = *(const bfx8*)&qh[src];
      pf_l[c] = *(const bfx8*)&ql[src];
    }
  };
  // V^T global layout: [b][n=hd*64+dh][s]; tile rows are dh, cols are keys
  auto loadVT = [&](int vt) {
    #pragma unroll
    for (int c = 0; c < 2; ++c) {
      int row = srow8 + c*32;                    // dh-local
      size_t src = ((size_t)b*D_ + hd*64 + row) * S_ + vt*64 + scol8;
      pf_h[c] = *(const bfx8*)&vth[src];
      pf_l[c] = *(const bfx8*)&vtl[src];
    }
  };

  // ---- phase 1: scores ----
  loadK(0);
  for (int kt = 0; kt < nkt; ++kt) {
    #pragma unroll
    for (int c = 0; c < 2; ++c) {
      int row = srow8 + c*32;
      *(bfx8*)&KVh[row*LDV + scol8] = pf_h[c];
      *(bfx8*)&KVl[row*LDV + scol8] = pf_l[c];
    }
    __syncthreads();
    if (kt + 1 < nkt) loadK(kt + 1);   // overlap next fetch with MFMA
    floatx4 acc = (floatx4){0.f, 0.f, 0.f, 0.f};
    __builtin_amdgcn_s_setprio(1);
    #pragma unroll
    for (int ks = 0; ks < 2; ++ks) {
      bfx8 kbh = *(const bfx8*)&KVh[(w*16 + r16)*LDV + ks*32 + q4*8];
      bfx8 kbl = *(const bfx8*)&KVl[(w*16 + r16)*LDV + ks*32 + q4*8];
      acc = mfma_bf16(qf[ks][0], kbh, acc);
      acc = mfma_bf16(qf[ks][0], kbl, acc);
      acc = mfma_bf16(qf[ks][1], kbh, acc);
    }
    __builtin_amdgcn_s_setprio(0);
    int gcol = kt*64 + w*16 + r16;
    #pragma unroll
    for (int r = 0; r < 4; ++r) {
      int lrow = q4*4 + r;
      int grow = qt*16 + lrow;
      float sc = acc[r] * 0.125f;          // / sqrt(64)
      if (gcol >= grow) sc = -1e32f;       // strictly causal (tril k=-1)
      Ssc[lrow*LSS + gcol] = sc;
    }
    __syncthreads();
  }

  loadVT(0);                               // hide V^T tile 0 under softmax

  // ---- phase 2: softmax + exact top-5 re-softmax (wave w owns rows w*4..+3)
  // final P written as bf16 hi/lo within the row's Ssc footprint:
  //   row byte base = lrow*LSS*4; hi at [key], lo at [512+key]  (2048B <= 2064B)
  for (int rr = 0; rr < 4; ++rr) {
    int lrow = w*4 + rr;
    int grow = qt*16 + lrow;
    float p[8];
    float mx = -3.0e38f;
    #pragma unroll
    for (int j = 0; j < 8; ++j) {
      p[j] = (j < nkt) ? Ssc[lrow*LSS + j*64 + lane] : -1e32f;
      mx = fmaxf(mx, p[j]);
    }
    mx = wave_max(mx);
    float s = 0.f;
    #pragma unroll
    for (int j = 0; j < 8; ++j) { p[j] = __expf(p[j] - mx); s += p[j]; }
    s = wave_sum(s);
    float invs = 1.0f / s;
    #pragma unroll
    for (int j = 0; j < 8; ++j) p[j] *= invs;   // masked j: exp -> 0
    if (grow == 0) {                                   // zero_pad row
      #pragma unroll
      for (int j = 0; j < 8; ++j) p[j] = 0.f;
    } else if (grow > 5) {
      // exact 5th order statistic (with duplicates, matching lax.top_k)
      unsigned rm = 0;
      float pmax = 0.f, thr = 0.f;
      for (int it = 0; it < 5; ++it) {
        float loc = -1.f; int locj = 0;
        #pragma unroll
        for (int j = 0; j < 8; ++j)
          if (!((rm >> j) & 1u) && p[j] > loc) { loc = p[j]; locj = j; }
        float wmx = wave_max(loc);
        if (it == 0) pmax = wmx;
        thr = wmx;
        unsigned long long ball = __ballot(loc == wmx);
        int first = (int)__builtin_ctzll(ball);          // remove one instance
        if (lane == first) rm |= 1u << locj;
      }
      float s2 = 0.f;
      #pragma unroll
      for (int j = 0; j < 8; ++j) {
        float vv = (p[j] - thr >= 0.f) ? __expf(p[j] - pmax) : 0.f;
        p[j] = vv; s2 += vv;
      }
      s2 = wave_sum(s2);
      float invs2 = 1.0f / s2;
      #pragma unroll
      for (int j = 0; j < 8; ++j) p[j] *= invs2;
    }
    // grow in [1,5]: plain softmax row, p already final
    __bf16* Prow = (__bf16*)&Ssc[lrow*LSS];
    #pragma unroll
    for (int j = 0; j < 8; ++j)
      if (j < nkt) {
        int key = j*64 + lane;
        float f = p[j];
        __bf16 hv = (__bf16)f;
        Prow[key]       = hv;
        Prow[512 + key] = (__bf16)(f - (float)hv);
      }
  }

  // ---- phase 3: O^T = V^T @ P^T (swapped operands), all-vector LDS ----
  floatx4 oacc = (floatx4){0.f, 0.f, 0.f, 0.f};
  for (int vt = 0; vt < nkt; ++vt) {
    #pragma unroll
    for (int c = 0; c < 2; ++c) {
      int row = srow8 + c*32;
      *(bfx8*)&KVh[row*LDV + scol8] = pf_h[c];
      *(bfx8*)&KVl[row*LDV + scol8] = pf_l[c];
    }
    __syncthreads();                  // also orders phase-2 Ssc writes
    if (vt + 1 < nkt) loadVT(vt + 1);
    const __bf16* Pr = (const __bf16*)&Ssc[r16*LSS];
    __builtin_amdgcn_s_setprio(1);
    #pragma unroll
    for (int ks = 0; ks < 2; ++ks) {
      // A-frag: V^T[m=dh_local][k=key_local], vector b128 (tile is [dh][key])
      bfx8 vfh = *(const bfx8*)&KVh[(w*16 + r16)*LDV + ks*32 + q4*8];
      bfx8 vfl = *(const bfx8*)&KVl[(w*16 + r16)*LDV + ks*32 + q4*8];
      // B-frag: P^T[k][n=q] = P[q=r16][key], pre-split bf16 hi/lo, b128 reads
      bfx8 ph = *(const bfx8*)&Pr[vt*64 + ks*32 + q4*8];
      bfx8 pl = *(const bfx8*)&Pr[512 + vt*64 + ks*32 + q4*8];
      oacc = mfma_bf16(vfh, ph, oacc);
      oacc = mfma_bf16(vfh, pl, oacc);
      oacc = mfma_bf16(vfl, ph, oacc);
    }
    __builtin_amdgcn_s_setprio(0);
    __syncthreads();
  }
  // D^T layout: col(lane&15) = q_local, row(q4*4+r) = dh_local in chunk w*16
  #pragma unroll
  for (int r = 0; r < 4; ++r) {
    int grow = qt*16 + r16;
    int dh  = w*16 + q4*4 + r;
    size_t off = ((size_t)(b*S_ + grow)) * D_ + hd*64 + dh;
    float val = oacc[r];
    __bf16 hv = (__bf16)val;
    oh[off] = hv;
    ol[off] = (__bf16)(val - (float)hv);
  }
}

// ---------------------------------------------------------------------------
// residual + LayerNorm (fp32): x = LN(xh+xl + th+tl); writes bf16 hi/lo pair
// and (if fout) the exact fp32 result. 1 wave/row, 4 rows/block.
// ---------------------------------------------------------------------------
__global__ void resid_ln_kernel(const __bf16* __restrict__ xhin, const __bf16* __restrict__ xlin,
                                const __bf16* __restrict__ thin, const __bf16* __restrict__ tlin,
                                const float* __restrict__ g, const float* __restrict__ bb,
                                __bf16* __restrict__ xh, __bf16* __restrict__ xl,
                                float* __restrict__ fout)
{
  int row = blockIdx.x * 4 + (threadIdx.x >> 6);
  int lane = threadIdx.x & 63;
  size_t base = (size_t)row * D_ + lane * 8;
  bfx8 h8 = *(const bfx8*)(xhin + base);
  bfx8 l8 = *(const bfx8*)(xlin + base);
  bfx8 th8 = *(const bfx8*)(thin + base);
  bfx8 tl8 = *(const bfx8*)(tlin + base);
  float v[8];
  #pragma unroll
  for (int j = 0; j < 8; ++j)
    v[j] = ((float)h8[j] + (float)l8[j]) + ((float)th8[j] + (float)tl8[j]);
  float s = 0.f;
  #pragma unroll
  for (int j = 0; j < 8; ++j) s += v[j];
  s = wave_sum(s);
  float mean = s * (1.0f/512.0f);
  float var = 0.f;
  #pragma unroll
  for (int j = 0; j < 8; ++j) { float d = v[j] - mean; var += d*d; }
  var = wave_sum(var) * (1.0f/512.0f);
  float rs = 1.0f / sqrtf(var + 1e-5f);
  float4 g0 = *(const float4*)(g + lane*8);
  float4 g1 = *(const float4*)(g + lane*8 + 4);
  float4 b0 = *(const float4*)(bb + lane*8);
  float4 b1 = *(const float4*)(bb + lane*8 + 4);
  float gg[8]  = {g0.x,g0.y,g0.z,g0.w,g1.x,g1.y,g1.z,g1.w};
  float bbv[8] = {b0.x,b0.y,b0.z,b0.w,b1.x,b1.y,b1.z,b1.w};
  float o[8];
  #pragma unroll
  for (int j = 0; j < 8; ++j) o[j] = (v[j] - mean) * rs * gg[j] + bbv[j];
  bfx8 hv8, lv8;
  #pragma unroll
  for (int j = 0; j < 8; ++j) {
    __bf16 hv = (__bf16)o[j];
    hv8[j] = hv;
    lv8[j] = (__bf16)(o[j] - (float)hv);
  }
  *(bfx8*)(xh + base) = hv8;
  *(bfx8*)(xl + base) = lv8;
  if (fout) {
    *(float4*)(fout + base)     = make_float4(o[0],o[1],o[2],o[3]);
    *(float4*)(fout + base + 4) = make_float4(o[4],o[5],o[6],o[7]);
  }
}

// ---------------------------------------------------------------------------
extern "C" void kernel_launch(void* const* d_in, const int* in_sizes, int n_in,
                              void* d_out, int out_size, void* d_ws, size_t ws_size,
                              hipStream_t stream)
{
  const float* qe   = (const float*)d_in[0];
  const float* ie   = (const float*)d_in[1];
  const float* pos  = (const float*)d_in[2];
  const float* Wk   = (const float*)d_in[3];
  const float* bk   = (const float*)d_in[4];
  const float* Wv   = (const float*)d_in[5];
  const float* bv   = (const float*)d_in[6];
  const float* Wo   = (const float*)d_in[7];
  const float* bo   = (const float*)d_in[8];
  const float* ln1g = (const float*)d_in[9];
  const float* ln1b = (const float*)d_in[10];
  const float* W1   = (const float*)d_in[11];
  const float* b1   = (const float*)d_in[12];
  const float* W2   = (const float*)d_in[13];
  const float* b2   = (const float*)d_in[14];
  const float* ln2g = (const float*)d_in[15];
  const float* ln2b = (const float*)d_in[16];

  char* wsp = (char*)d_ws;
  size_t off = 0;
  auto alloc = [&](size_t bytes) -> void* {
    void* p = wsp + off;
    off += (bytes + 255) & ~(size_t)255;
    return p;
  };
  const size_t NB = (size_t)BS_ * D_ * sizeof(__bf16);   // 16 MB per bf16 activation
  __bf16* xh  = (__bf16*)alloc(NB);
  __bf16* xl  = (__bf16*)alloc(NB);
  // q region aliases t (attn-out-proj / FFN2 result): q dead once out-proj runs
  char*   qt_ = (char*)  alloc(2*NB);
  __bf16* qhb = (__bf16*)qt_;
  __bf16* qlb = (__bf16*)(qt_ + NB);
  __bf16* thb = (__bf16*)qt_;
  __bf16* tlb = (__bf16*)(qt_ + NB);
  __bf16* vhb = (__bf16*)alloc(NB);       // V^T hi ([b][n][s])
  __bf16* vlb = (__bf16*)alloc(NB);       // V^T lo
  // o region (2*NB) aliases FFN hidden-hi (M=8192: 8192*2048*2B = 32MB = 2*NB)
  char*   oh_ = (char*) alloc(2*NB);
  __bf16* ohb = (__bf16*)oh_;
  __bf16* olb = (__bf16*)(oh_ + NB);
  __bf16* hhb = (__bf16*)oh_;
  __bf16* hlb = (__bf16*)alloc(2*NB);      // hidden-lo, 32 MB
  const size_t LW = 3*(size_t)D_*D_ + 2*(size_t)D_*DFF_;   // elems / layer
  __bf16* wth = (__bf16*)alloc(2*LW*sizeof(__bf16));
  __bf16* wtl = (__bf16*)alloc(2*LW*sizeof(__bf16));
  // y = ie + pos as bf16 hi/lo (allocated LAST; used only if ws fits)
  __bf16* yh = (__bf16*)alloc(NB);
  __bf16* yl = (__bf16*)alloc(NB);
  const bool have_y = (off <= ws_size);
  float*  xout = (float*)d_out;
  // total ws usage ~216 MB with y, ~184 MB without

  const size_t OK = 0, OV = (size_t)D_*D_, OO = 2*(size_t)D_*D_;
  const size_t O1 = 3*(size_t)D_*D_, O2 = 3*(size_t)D_*D_ + (size_t)D_*DFF_;

  // weight transposes + splits (recomputed each call; graph-capture safe)
  for (int l = 0; l < L_; ++l) {
    size_t base = (size_t)l * LW;
    transpose_split_kernel<<<dim3(16,16), 256, 0, stream>>>(Wk + (size_t)l*D_*D_,   wth+base+OK, wtl+base+OK, D_,  D_);
    transpose_split_kernel<<<dim3(16,16), 256, 0, stream>>>(Wv + (size_t)l*D_*D_,   wth+base+OV, wtl+base+OV, D_,  D_);
    transpose_split_kernel<<<dim3(16,16), 256, 0, stream>>>(Wo + (size_t)l*D_*D_,   wth+base+OO, wtl+base+OO, D_,  D_);
    transpose_split_kernel<<<dim3(64,16), 256, 0, stream>>>(W1 + (size_t)l*D_*DFF_, wth+base+O1, wtl+base+O1, D_,  DFF_);
    transpose_split_kernel<<<dim3(16,64), 256, 0, stream>>>(W2 + (size_t)l*DFF_*D_, wth+base+O2, wtl+base+O2, DFF_, D_);
  }

  init_x_kernel<<<4096, 256, 0, stream>>>(qe, pos, xh, xl);
  if (have_y)
    init_x_kernel<<<4096, 256, 0, stream>>>(ie, pos, yh, yl);

  for (int l = 0; l < L_; ++l) {
    size_t base = (size_t)l * LW;
    // q = k = x @ Wk + bk (kq_same), bf16 hi/lo out
    gemm_split3_kernel<<<dim3(4,128), 256, 0, stream>>>(xh, xl, nullptr, nullptr,
        wth+base+OK, wtl+base+OK, bk + (size_t)l*D_, qhb, qlb, BS_, D_, D_, 0);
    // v^T = ((ie + pos) @ Wv + bv)^T per batch
    if (have_y)   // fast DMA path: y precomputed, bit-identical values
      gemm_split3_kernel<<<dim3(4,128), 256, 0, stream>>>(yh, yl, nullptr, nullptr,
          wth+base+OV, wtl+base+OV, bv + (size_t)l*D_, vhb, vlb, BS_, D_, D_, 8);
    else          // fallback: fused fp32 y staging
      gemm_split3_kernel<<<dim3(4,128), 256, 0, stream>>>(nullptr, nullptr, ie, pos,
          wth+base+OV, wtl+base+OV, bv + (size_t)l*D_, vhb, vlb, BS_, D_, D_, 4|8);
    // sparse attention (1-D grid, XCD-affine decode inside)
    attn_kernel<<<dim3(32*H_*B_), 256, 0, stream>>>(qhb, qlb, vhb, vlb, ohb, olb);
    // out-proj -> t (hi/lo; overwrites q region, q is dead)
    gemm_split3_kernel<<<dim3(4,128), 256, 0, stream>>>(ohb, olb, nullptr, nullptr,
        wth+base+OO, wtl+base+OO, bo + (size_t)l*D_, thb, tlb, BS_, D_, D_, 0);
    // x = LN1(x + t)
    resid_ln_kernel<<<BS_/4, 256, 0, stream>>>(xh, xl, thb, tlb,
        ln1g + (size_t)l*D_, ln1b + (size_t)l*D_, xh, xl, nullptr);
    // FFN in two M=8192 chunks (hidden-hi aliases o region, out -> t region)
    for (int ch = 0; ch < 2; ++ch) {
      size_t ao = (size_t)ch*8192*D_;
      gemm_split3_kernel<<<dim3(16,64), 256, 0, stream>>>(xh + ao, xl + ao, nullptr, nullptr,
          wth+base+O1, wtl+base+O1, b1 + (size_t)l*DFF_, hhb, hlb, 8192, DFF_, D_, 1);
      gemm_split3_kernel<<<dim3(4,64), 256, 0, stream>>>(hhb, hlb, nullptr, nullptr,
          wth+base+O2, wtl+base+O2, b2 + (size_t)l*D_, thb + ao, tlb + ao, 8192, D_, DFF_, 0);
    }
    // x = LN2(x + t); final layer writes fp32 straight to d_out
    resid_ln_kernel<<<BS_/4, 256, 0, stream>>>(xh, xl, thb, tlb,
        ln2g + (size_t)l*D_, ln2b + (size_t)l*D_, xh, xl,
        (l == L_-1) ? xout : nullptr);
  }
}

// Round 4
// 1384.837 us; speedup vs baseline: 1.0345x; 1.0345x over previous
//
#include <hip/hip_runtime.h>

// ---------------------------------------------------------------------------
// SparseKT forward, MI355X gfx950. I/O dtype: fp32 (per reference).
// Numerics: fp32 tensors decomposed into hi/lo bf16 pairs (pseudo-fp32,
// rel err ~2^-17). GEMMs are split-3: C = Ah*Bh + Ah*Bl + Al*Bh (3 MFMAs).
// Softmax / exact top-5 / LayerNorm in fp32. Residual stream: hi/lo pairs.
// R8->R9 (both changes bit-identical numerics):
//   (a) attn: K/V LDS staging REMOVED -- audit showed each staged element is
//       read exactly once by exactly one lane (no reuse), so fragments now
//       load directly global->registers (same addresses, same MFMA order).
//       Deletes 2 barriers + 8 ds_writes per tile per phase; LDS 51.7->33 KB
//       => 4 blocks/CU. Depth-1 register prefetch of next tile's fragments.
//   (b) GEMM: 2-phase double-buffered LDS (T3-minimum): stage tile t+1 is
//       issued BEFORE compute of tile t; ONE __syncthreads per K-step (its
//       implicit vmcnt(0) drains the DMA after MFMA covered the latency).
// ---------------------------------------------------------------------------

#define L_   2
#define B_   32
#define S_   512
#define D_   512
#define H_   8
#define DH_  64
#define DFF_ 2048
#define BS_  (B_*S_)      // 16384

typedef __bf16 bfx8 __attribute__((ext_vector_type(8)));
typedef __bf16 bfx4 __attribute__((ext_vector_type(4)));
typedef float floatx4 __attribute__((ext_vector_type(4)));

__device__ __forceinline__ floatx4 mfma_bf16(bfx8 a, bfx8 b, floatx4 c) {
  return __builtin_amdgcn_mfma_f32_16x16x32_bf16(a, b, c, 0, 0, 0);
}

__device__ __forceinline__ float wave_sum(float v) {
  #pragma unroll
  for (int d = 32; d > 0; d >>= 1) v += __shfl_xor(v, d);
  return v;
}
__device__ __forceinline__ float wave_max(float v) {
  #pragma unroll
  for (int d = 32; d > 0; d >>= 1) v = fmaxf(v, __shfl_xor(v, d));
  return v;
}

// async global->LDS, 16 B per lane; LDS dest = wave-uniform base + lane*16
__device__ __forceinline__ void lds_load16(__bf16* lds, const __bf16* g) {
  __builtin_amdgcn_global_load_lds(
      (const __attribute__((address_space(1))) unsigned int*)g,
      (__attribute__((address_space(3))) unsigned int*)lds, 16, 0, 0);
}

// LDS chunk swizzle: logical 8-elem chunk q of row r stored at q ^ ((r>>1)&3)
__device__ __forceinline__ int swz(int row, int q) { return q ^ ((row >> 1) & 3); }

// ---------------------------------------------------------------------------
// init: x = emb + pos (fp32) -> bf16 hi/lo pair (used for both qe and ie)
// ---------------------------------------------------------------------------
__global__ void init_x_kernel(const float* __restrict__ qe, const float* __restrict__ pos,
                              __bf16* __restrict__ xh, __bf16* __restrict__ xl)
{
  size_t i = ((size_t)blockIdx.x * 256 + threadIdx.x) * 8;
  float4 a0 = *(const float4*)(qe + i);
  float4 a1 = *(const float4*)(qe + i + 4);
  size_t pi = i & (size_t)(S_*D_ - 1);
  float4 p0 = *(const float4*)(pos + pi);
  float4 p1 = *(const float4*)(pos + pi + 4);
  float v[8] = {a0.x+p0.x, a0.y+p0.y, a0.z+p0.z, a0.w+p0.w,
                a1.x+p1.x, a1.y+p1.y, a1.z+p1.z, a1.w+p1.w};
  bfx8 hv8, lv8;
  #pragma unroll
  for (int j = 0; j < 8; ++j) {
    __bf16 hv = (__bf16)v[j];
    hv8[j] = hv;
    lv8[j] = (__bf16)(v[j] - (float)hv);
  }
  *(bfx8*)(xh + i) = hv8;
  *(bfx8*)(xl + i) = lv8;
}

// ---------------------------------------------------------------------------
// weight transpose + hi/lo split:  W[K][N] fp32  ->  T{h,l}[N][K] bf16
// ---------------------------------------------------------------------------
__global__ void transpose_split_kernel(const float* __restrict__ Wsrc,
                                       __bf16* __restrict__ Th, __bf16* __restrict__ Tl,
                                       int K, int N)
{
  __shared__ float tile[32][33];
  int n0 = blockIdx.x * 32, k0 = blockIdx.y * 32;
  int tx = threadIdx.x & 31, ty8 = threadIdx.x >> 5;  // 0..7
  #pragma unroll
  for (int j = 0; j < 4; ++j) {
    int k = ty8 + j*8;
    tile[k][tx] = Wsrc[(size_t)(k0 + k) * N + n0 + tx];
  }
  __syncthreads();
  #pragma unroll
  for (int j = 0; j < 4; ++j) {
    int n = ty8 + j*8;
    float vv = tile[tx][n];           // = W[k0+tx][n0+n]
    size_t dst = (size_t)(n0 + n) * K + k0 + tx;
    __bf16 hv = (__bf16)vv;
    Th[dst] = hv;
    Tl[dst] = (__bf16)(vv - (float)hv);
  }
}

// ---------------------------------------------------------------------------
// split-3 GEMM: C[M,N] = A[M,K] @ Bt[N,K]^T + bias; output bf16 hi/lo pair.
// flags: 1 = relu, 4 = stage A from fp32 (Afa[m] + Afp[m mod S]) on the fly
//        8 = write transposed per-batch output C^T[b][n][s] (b = m/S, s = m%S)
// 128x128x32 tile, 4 waves (64x64 quadrant each, 16 MFMA tiles).
// 2-phase double-buffered: stage(t+1) issued before compute(t); one barrier
// per K-step (implicit vmcnt(0)+lgkmcnt(0) at __syncthreads drains staging).
// Fast path (no flag 4): wave w DMA-stages buffer-kind w via global_load_lds.
// LDS XOR-swizzled (swz) -> conflict-free ds_read_b128 fragments, no padding.
// ---------------------------------------------------------------------------
__global__ __launch_bounds__(256, 2)
void gemm_split3_kernel(const __bf16* __restrict__ Ah, const __bf16* __restrict__ Al,
                        const float* __restrict__ Afa, const float* __restrict__ Afp,
                        const __bf16* __restrict__ Bth, const __bf16* __restrict__ Btl,
                        const float* __restrict__ bias,
                        __bf16* __restrict__ Ch, __bf16* __restrict__ Cl,
                        int M, int N, int K, int flags)
{
  __shared__ __bf16 sAh[2*128*32], sAl[2*128*32], sBh[2*128*32], sBl[2*128*32];
  const int t = threadIdx.x;
  const int w = t >> 6, lane = t & 63;
  const int q4 = lane >> 4, r16 = lane & 15;
  const int m0 = blockIdx.y * 128, n0 = blockIdx.x * 128;
  const int wm = (w >> 1) * 64, wn = (w & 1) * 64;

  floatx4 acc[4][4];
  #pragma unroll
  for (int i = 0; i < 4; ++i)
    #pragma unroll
    for (int j = 0; j < 4; ++j)
      acc[i][j] = (floatx4){0.f, 0.f, 0.f, 0.f};

  // fast-path per-wave staging assignment: wave w stages buffer-kind w
  const __bf16* wsrc = (w == 0) ? Ah : (w == 1) ? Al : (w == 2) ? Bth : Btl;
  __bf16* wdst = (w == 0) ? sAh : (w == 1) ? sAl : (w == 2) ? sBh : sBl;
  const int rbase = (w < 2) ? m0 : n0;
  const int rl = lane >> 2;        // row within 16-row group
  const int cp = lane & 3;         // physical chunk this lane fills

  // manual-path (flags&4) mapping
  const int srow = t >> 2;          // 0..63
  const int sq   = t & 3;           // logical chunk

  auto stage = [&](int k0, int bo) {
    if (!(flags & 4)) {
      #pragma unroll
      for (int g = 0; g < 8; ++g) {
        int row = g*16 + rl;
        int qc = swz(row, cp);       // logical chunk landing at phys cp
        const __bf16* gp = wsrc + (size_t)(rbase + row) * K + k0 + qc*8;
        lds_load16(wdst + bo + g*512, gp);
      }
    } else {
      #pragma unroll
      for (int c = 0; c < 2; ++c) {
        int row = srow + c * 64;
        size_t ga = (size_t)(m0 + row) * K + k0 + sq*8;
        size_t gp = (size_t)((m0 + row) & (S_ - 1)) * K + k0 + sq*8;
        float4 e0 = *(const float4*)&Afa[ga];
        float4 e1 = *(const float4*)&Afa[ga + 4];
        float4 p0 = *(const float4*)&Afp[gp];
        float4 p1 = *(const float4*)&Afp[gp + 4];
        float sv[8] = {e0.x+p0.x, e0.y+p0.y, e0.z+p0.z, e0.w+p0.w,
                       e1.x+p1.x, e1.y+p1.y, e1.z+p1.z, e1.w+p1.w};
        bfx8 hv8, lv8;
        #pragma unroll
        for (int j = 0; j < 8; ++j) {
          __bf16 hv = (__bf16)sv[j];
          hv8[j] = hv;
          lv8[j] = (__bf16)(sv[j] - (float)hv);
        }
        int pc = swz(row, sq);
        *(bfx8*)&sAh[bo + row*32 + pc*8] = hv8;
        *(bfx8*)&sAl[bo + row*32 + pc*8] = lv8;
        size_t gb = (size_t)(n0 + row) * K + k0 + sq*8;
        *(bfx8*)&sBh[bo + row*32 + pc*8] = *(const bfx8*)&Bth[gb];
        *(bfx8*)&sBl[bo + row*32 + pc*8] = *(const bfx8*)&Btl[gb];
      }
    }
  };

  const int nk = K >> 5;
  stage(0, 0);
  __syncthreads();
  int bo = 0;
  for (int it = 0; it < nk; ++it) {
    if (it + 1 < nk) stage((it + 1) << 5, bo ^ 4096);  // overlap with compute
    bfx8 af[4][2], bfr[4][2];
    #pragma unroll
    for (int i = 0; i < 4; ++i) {
      int ar = wm + i*16 + r16;
      int sa = swz(ar, q4) * 8;
      af[i][0] = *(const bfx8*)&sAh[bo + ar*32 + sa];
      af[i][1] = *(const bfx8*)&sAl[bo + ar*32 + sa];
      int br = wn + i*16 + r16;
      int sb = swz(br, q4) * 8;
      bfr[i][0] = *(const bfx8*)&sBh[bo + br*32 + sb];
      bfr[i][1] = *(const bfx8*)&sBl[bo + br*32 + sb];
    }
    #pragma unroll
    for (int i = 0; i < 4; ++i)
      #pragma unroll
      for (int j = 0; j < 4; ++j) {
        acc[i][j] = mfma_bf16(af[i][0], bfr[j][0], acc[i][j]);
        acc[i][j] = mfma_bf16(af[i][0], bfr[j][1], acc[i][j]);
        acc[i][j] = mfma_bf16(af[i][1], bfr[j][0], acc[i][j]);
      }
    __syncthreads();     // drains staging DMA (vmcnt) + orders buffer reuse
    bo ^= 4096;
  }

  // epilogue (C/D layout: col = lane&15, row = (lane>>4)*4 + reg  [m89-verified])
  if (flags & 8) {
    // transposed per-batch write: C^T[b][n][s]; 4 regs = 4 consecutive s -> 8B store
    #pragma unroll
    for (int i = 0; i < 4; ++i)
      #pragma unroll
      for (int j = 0; j < 4; ++j) {
        int gn = n0 + wn + j*16 + r16;
        float bb = bias[gn];
        int gmb = m0 + wm + i*16 + q4*4;
        size_t co = ((size_t)(gmb >> 9) * N + gn) * S_ + (gmb & (S_ - 1));
        bfx4 hv4, lv4;
        #pragma unroll
        for (int r = 0; r < 4; ++r) {
          float val = acc[i][j][r] + bb;
          if (flags & 1) val = fmaxf(val, 0.f);
          __bf16 hv = (__bf16)val;
          hv4[r] = hv;
          lv4[r] = (__bf16)(val - (float)hv);
        }
        *(bfx4*)(Ch + co) = hv4;
        *(bfx4*)(Cl + co) = lv4;
      }
  } else {
    #pragma unroll
    for (int i = 0; i < 4; ++i)
      #pragma unroll
      for (int j = 0; j < 4; ++j) {
        int gn = n0 + wn + j*16 + r16;
        float bb = bias[gn];
        #pragma unroll
        for (int r = 0; r < 4; ++r) {
          int gm = m0 + wm + i*16 + q4*4 + r;
          float val = acc[i][j][r] + bb;
          if (flags & 1) val = fmaxf(val, 0.f);
          size_t co = (size_t)gm * N + gn;
          __bf16 hv = (__bf16)val;
          Ch[co] = hv;
          Cl[co] = (__bf16)(val - (float)hv);
        }
      }
  }
}

// ---------------------------------------------------------------------------
// attention: 1-D grid 8192, decoded so batch b == XCD (lin&7): K/V of a batch
// stay L2-resident on one XCD. Heavy q-tiles first within each XCD.
// NO K/V LDS staging: each fragment element is consumed by exactly one lane
// exactly once, so B/A-frags load directly global->register (L2-served via
// XCD affinity). Only 2 barriers total (phase boundaries, cross-wave Ssc).
// phase 1: scores via MFMA (split-3), depth-1 register prefetch of K frags
// phase 2: softmax + exact top-5 re-softmax (unchanged); P -> bf16 hi/lo in Ssc
// phase 3: O^T = V^T @ P^T, V^T frags direct from global, depth-1 prefetch
// ---------------------------------------------------------------------------
__global__ __launch_bounds__(256, 4)
void attn_kernel(const __bf16* __restrict__ qh, const __bf16* __restrict__ ql,
                 const __bf16* __restrict__ vth, const __bf16* __restrict__ vtl,
                 __bf16* __restrict__ oh, __bf16* __restrict__ ol)
{
  constexpr int LSS = 516;                       // fp32 row stride (pad 4)
  __shared__ float Ssc[16*LSS];                  // 33 KB scores; P hi/lo after phase 2
  const int lin = blockIdx.x;
  const int xcd = lin & 7;
  const int ord = lin >> 3;                      // 0..1023 per xcd
  const int qt  = 31 - (ord & 31);               // heavy tiles first
  const int bh  = ord >> 5;                      // 0..31
  const int hd  = bh & 7;
  const int b   = ((bh >> 3) << 3) | xcd;        // b mod 8 == xcd
  const int t = threadIdx.x, w = t >> 6, lane = t & 63;
  const int q4 = lane >> 4, r16 = lane & 15;
  const int nkt = (qt >> 2) + 1;                 // 64-key tiles (causal)

  // Q fragments (A operand): rows qt*16+[0,16), cols hd*64+[0,64)
  bfx8 qf[2][2];
  {
    size_t base = ((size_t)(b*S_ + qt*16 + r16)) * D_ + hd*64;
    #pragma unroll
    for (int ks = 0; ks < 2; ++ks) {
      qf[ks][0] = *(const bfx8*)&qh[base + ks*32 + q4*8];
      qf[ks][1] = *(const bfx8*)&ql[base + ks*32 + q4*8];
    }
  }

  // fragment registers: current (c*) and prefetch (n*)
  bfx8 ch0, ch1, cl0, cl1, nh0, nh1, nl0, nl1;

  // ---- phase 1: scores; K B-frag row = kt*64 + w*16 + r16, col chunk q4*8 ----
  const size_t kstep = (size_t)64 * D_;
  const size_t kb0 = ((size_t)(b*S_ + w*16 + r16)) * D_ + hd*64 + q4*8;
  ch0 = *(const bfx8*)&qh[kb0];
  ch1 = *(const bfx8*)&qh[kb0 + 32];
  cl0 = *(const bfx8*)&ql[kb0];
  cl1 = *(const bfx8*)&ql[kb0 + 32];
  for (int kt = 0; kt < nkt; ++kt) {
    const bool more = (kt + 1 < nkt);
    if (more) {
      size_t nb = kb0 + (size_t)(kt + 1) * kstep;
      nh0 = *(const bfx8*)&qh[nb];
      nh1 = *(const bfx8*)&qh[nb + 32];
      nl0 = *(const bfx8*)&ql[nb];
      nl1 = *(const bfx8*)&ql[nb + 32];
    }
    floatx4 acc = (floatx4){0.f, 0.f, 0.f, 0.f};
    __builtin_amdgcn_s_setprio(1);
    acc = mfma_bf16(qf[0][0], ch0, acc);   // same order as staged version:
    acc = mfma_bf16(qf[0][0], cl0, acc);   // ks=0: h,l,h  then ks=1: h,l,h
    acc = mfma_bf16(qf[0][1], ch0, acc);
    acc = mfma_bf16(qf[1][0], ch1, acc);
    acc = mfma_bf16(qf[1][0], cl1, acc);
    acc = mfma_bf16(qf[1][1], ch1, acc);
    __builtin_amdgcn_s_setprio(0);
    int gcol = kt*64 + w*16 + r16;
    #pragma unroll
    for (int r = 0; r < 4; ++r) {
      int lrow = q4*4 + r;
      int grow = qt*16 + lrow;
      float sc = acc[r] * 0.125f;          // / sqrt(64)
      if (gcol >= grow) sc = -1e32f;       // strictly causal (tril k=-1)
      Ssc[lrow*LSS + gcol] = sc;
    }
    if (more) { ch0 = nh0; ch1 = nh1; cl0 = nl0; cl1 = nl1; }
  }
  __syncthreads();                         // phase-1 Ssc writes -> phase-2 reads

  // ---- phase 2: softmax + exact top-5 re-softmax (wave w owns rows w*4..+3)
  // final P written as bf16 hi/lo within the row's Ssc footprint:
  //   row byte base = lrow*LSS*4; hi at [key], lo at [512+key]  (2048B <= 2064B)
  for (int rr = 0; rr < 4; ++rr) {
    int lrow = w*4 + rr;
    int grow = qt*16 + lrow;
    float p[8];
    float mx = -3.0e38f;
    #pragma unroll
    for (int j = 0; j < 8; ++j) {
      p[j] = (j < nkt) ? Ssc[lrow*LSS + j*64 + lane] : -1e32f;
      mx = fmaxf(mx, p[j]);
    }
    mx = wave_max(mx);
    float s = 0.f;
    #pragma unroll
    for (int j = 0; j < 8; ++j) { p[j] = __expf(p[j] - mx); s += p[j]; }
    s = wave_sum(s);
    float invs = 1.0f / s;
    #pragma unroll
    for (int j = 0; j < 8; ++j) p[j] *= invs;   // masked j: exp -> 0
    if (grow == 0) {                                   // zero_pad row
      #pragma unroll
      for (int j = 0; j < 8; ++j) p[j] = 0.f;
    } else if (grow > 5) {
      // exact 5th order statistic (with duplicates, matching lax.top_k)
      unsigned rm = 0;
      float pmax = 0.f, thr = 0.f;
      for (int it = 0; it < 5; ++it) {
        float loc = -1.f; int locj = 0;
        #pragma unroll
        for (int j = 0; j < 8; ++j)
          if (!((rm >> j) & 1u) && p[j] > loc) { loc = p[j]; locj = j; }
        float wmx = wave_max(loc);
        if (it == 0) pmax = wmx;
        thr = wmx;
        unsigned long long ball = __ballot(loc == wmx);
        int first = (int)__builtin_ctzll(ball);          // remove one instance
        if (lane == first) rm |= 1u << locj;
      }
      float s2 = 0.f;
      #pragma unroll
      for (int j = 0; j < 8; ++j) {
        float vv = (p[j] - thr >= 0.f) ? __expf(p[j] - pmax) : 0.f;
        p[j] = vv; s2 += vv;
      }
      s2 = wave_sum(s2);
      float invs2 = 1.0f / s2;
      #pragma unroll
      for (int j = 0; j < 8; ++j) p[j] *= invs2;
    }
    // grow in [1,5]: plain softmax row, p already final
    __bf16* Prow = (__bf16*)&Ssc[lrow*LSS];
    #pragma unroll
    for (int j = 0; j < 8; ++j)
      if (j < nkt) {
        int key = j*64 + lane;
        float f = p[j];
        __bf16 hv = (__bf16)f;
        Prow[key]       = hv;
        Prow[512 + key] = (__bf16)(f - (float)hv);
      }
  }
  __syncthreads();                         // phase-2 P writes -> phase-3 reads

  // ---- phase 3: O^T = V^T @ P^T; V^T frag row = hd*64 + w*16 + r16 (dh),
  //      cols = vt*64 + chunk (keys), direct from global ----
  const size_t vb0 = ((size_t)(b*D_ + hd*64 + w*16 + r16)) * S_ + q4*8;
  ch0 = *(const bfx8*)&vth[vb0];
  ch1 = *(const bfx8*)&vth[vb0 + 32];
  cl0 = *(const bfx8*)&vtl[vb0];
  cl1 = *(const bfx8*)&vtl[vb0 + 32];
  floatx4 oacc = (floatx4){0.f, 0.f, 0.f, 0.f};
  const __bf16* Pr = (const __bf16*)&Ssc[r16*LSS];
  for (int vt = 0; vt < nkt; ++vt) {
    const bool more = (vt + 1 < nkt);
    if (more) {
      size_t nb = vb0 + (size_t)(vt + 1) * 64;
      nh0 = *(const bfx8*)&vth[nb];
      nh1 = *(const bfx8*)&vth[nb + 32];
      nl0 = *(const bfx8*)&vtl[nb];
      nl1 = *(const bfx8*)&vtl[nb + 32];
    }
    bfx8 ph0 = *(const bfx8*)&Pr[vt*64 + q4*8];
    bfx8 pl0 = *(const bfx8*)&Pr[512 + vt*64 + q4*8];
    bfx8 ph1 = *(const bfx8*)&Pr[vt*64 + 32 + q4*8];
    bfx8 pl1 = *(const bfx8*)&Pr[512 + vt*64 + 32 + q4*8];
    __builtin_amdgcn_s_setprio(1);
    oacc = mfma_bf16(ch0, ph0, oacc);      // same order: ks=0 h,l,h; ks=1 h,l,h
    oacc = mfma_bf16(ch0, pl0, oacc);
    oacc = mfma_bf16(cl0, ph0, oacc);
    oacc = mfma_bf16(ch1, ph1, oacc);
    oacc = mfma_bf16(ch1, pl1, oacc);
    oacc = mfma_bf16(cl1, ph1, oacc);
    __builtin_amdgcn_s_setprio(0);
    if (more) { ch0 = nh0; ch1 = nh1; cl0 = nl0; cl1 = nl1; }
  }
  // D^T layout: col(lane&15) = q_local, row(q4*4+r) = dh_local in chunk w*16
  #pragma unroll
  for (int r = 0; r < 4; ++r) {
    int grow = qt*16 + r16;
    int dh  = w*16 + q4*4 + r;
    size_t off = ((size_t)(b*S_ + grow)) * D_ + hd*64 + dh;
    float val = oacc[r];
    __bf16 hv = (__bf16)val;
    oh[off] = hv;
    ol[off] = (__bf16)(val - (float)hv);
  }
}

// ---------------------------------------------------------------------------
// residual + LayerNorm (fp32): x = LN(xh+xl + th+tl); writes bf16 hi/lo pair
// and (if fout) the exact fp32 result. 1 wave/row, 4 rows/block.
// ---------------------------------------------------------------------------
__global__ void resid_ln_kernel(const __bf16* __restrict__ xhin, const __bf16* __restrict__ xlin,
                                const __bf16* __restrict__ thin, const __bf16* __restrict__ tlin,
                                const float* __restrict__ g, const float* __restrict__ bb,
                                __bf16* __restrict__ xh, __bf16* __restrict__ xl,
                                float* __restrict__ fout)
{
  int row = blockIdx.x * 4 + (threadIdx.x >> 6);
  int lane = threadIdx.x & 63;
  size_t base = (size_t)row * D_ + lane * 8;
  bfx8 h8 = *(const bfx8*)(xhin + base);
  bfx8 l8 = *(const bfx8*)(xlin + base);
  bfx8 th8 = *(const bfx8*)(thin + base);
  bfx8 tl8 = *(const bfx8*)(tlin + base);
  float v[8];
  #pragma unroll
  for (int j = 0; j < 8; ++j)
    v[j] = ((float)h8[j] + (float)l8[j]) + ((float)th8[j] + (float)tl8[j]);
  float s = 0.f;
  #pragma unroll
  for (int j = 0; j < 8; ++j) s += v[j];
  s = wave_sum(s);
  float mean = s * (1.0f/512.0f);
  float var = 0.f;
  #pragma unroll
  for (int j = 0; j < 8; ++j) { float d = v[j] - mean; var += d*d; }
  var = wave_sum(var) * (1.0f/512.0f);
  float rs = 1.0f / sqrtf(var + 1e-5f);
  float4 g0 = *(const float4*)(g + lane*8);
  float4 g1 = *(const float4*)(g + lane*8 + 4);
  float4 b0 = *(const float4*)(bb + lane*8);
  float4 b1 = *(const float4*)(bb + lane*8 + 4);
  float gg[8]  = {g0.x,g0.y,g0.z,g0.w,g1.x,g1.y,g1.z,g1.w};
  float bbv[8] = {b0.x,b0.y,b0.z,b0.w,b1.x,b1.y,b1.z,b1.w};
  float o[8];
  #pragma unroll
  for (int j = 0; j < 8; ++j) o[j] = (v[j] - mean) * rs * gg[j] + bbv[j];
  bfx8 hv8, lv8;
  #pragma unroll
  for (int j = 0; j < 8; ++j) {
    __bf16 hv = (__bf16)o[j];
    hv8[j] = hv;
    lv8[j] = (__bf16)(o[j] - (float)hv);
  }
  *(bfx8*)(xh + base) = hv8;
  *(bfx8*)(xl + base) = lv8;
  if (fout) {
    *(float4*)(fout + base)     = make_float4(o[0],o[1],o[2],o[3]);
    *(float4*)(fout + base + 4) = make_float4(o[4],o[5],o[6],o[7]);
  }
}

// ---------------------------------------------------------------------------
extern "C" void kernel_launch(void* const* d_in, const int* in_sizes, int n_in,
                              void* d_out, int out_size, void* d_ws, size_t ws_size,
                              hipStream_t stream)
{
  const float* qe   = (const float*)d_in[0];
  const float* ie   = (const float*)d_in[1];
  const float* pos  = (const float*)d_in[2];
  const float* Wk   = (const float*)d_in[3];
  const float* bk   = (const float*)d_in[4];
  const float* Wv   = (const float*)d_in[5];
  const float* bv   = (const float*)d_in[6];
  const float* Wo   = (const float*)d_in[7];
  const float* bo   = (const float*)d_in[8];
  const float* ln1g = (const float*)d_in[9];
  const float* ln1b = (const float*)d_in[10];
  const float* W1   = (const float*)d_in[11];
  const float* b1   = (const float*)d_in[12];
  const float* W2   = (const float*)d_in[13];
  const float* b2   = (const float*)d_in[14];
  const float* ln2g = (const float*)d_in[15];
  const float* ln2b = (const float*)d_in[16];

  char* wsp = (char*)d_ws;
  size_t off = 0;
  auto alloc = [&](size_t bytes) -> void* {
    void* p = wsp + off;
    off += (bytes + 255) & ~(size_t)255;
    return p;
  };
  const size_t NB = (size_t)BS_ * D_ * sizeof(__bf16);   // 16 MB per bf16 activation
  __bf16* xh  = (__bf16*)alloc(NB);
  __bf16* xl  = (__bf16*)alloc(NB);
  // q region aliases t (attn-out-proj / FFN2 result): q dead once out-proj runs
  char*   qt_ = (char*)  alloc(2*NB);
  __bf16* qhb = (__bf16*)qt_;
  __bf16* qlb = (__bf16*)(qt_ + NB);
  __bf16* thb = (__bf16*)qt_;
  __bf16* tlb = (__bf16*)(qt_ + NB);
  __bf16* vhb = (__bf16*)alloc(NB);       // V^T hi ([b][n][s])
  __bf16* vlb = (__bf16*)alloc(NB);       // V^T lo
  // o region (2*NB) aliases FFN hidden-hi (M=8192: 8192*2048*2B = 32MB = 2*NB)
  char*   oh_ = (char*) alloc(2*NB);
  __bf16* ohb = (__bf16*)oh_;
  __bf16* olb = (__bf16*)(oh_ + NB);
  __bf16* hhb = (__bf16*)oh_;
  __bf16* hlb = (__bf16*)alloc(2*NB);      // hidden-lo, 32 MB
  const size_t LW = 3*(size_t)D_*D_ + 2*(size_t)D_*DFF_;   // elems / layer
  __bf16* wth = (__bf16*)alloc(2*LW*sizeof(__bf16));
  __bf16* wtl = (__bf16*)alloc(2*LW*sizeof(__bf16));
  // y = ie + pos as bf16 hi/lo (allocated LAST; used only if ws fits)
  __bf16* yh = (__bf16*)alloc(NB);
  __bf16* yl = (__bf16*)alloc(NB);
  const bool have_y = (off <= ws_size);
  float*  xout = (float*)d_out;
  // total ws usage ~216 MB with y, ~184 MB without

  const size_t OK = 0, OV = (size_t)D_*D_, OO = 2*(size_t)D_*D_;
  const size_t O1 = 3*(size_t)D_*D_, O2 = 3*(size_t)D_*D_ + (size_t)D_*DFF_;

  // weight transposes + splits (recomputed each call; graph-capture safe)
  for (int l = 0; l < L_; ++l) {
    size_t base = (size_t)l * LW;
    transpose_split_kernel<<<dim3(16,16), 256, 0, stream>>>(Wk + (size_t)l*D_*D_,   wth+base+OK, wtl+base+OK, D_,  D_);
    transpose_split_kernel<<<dim3(16,16), 256, 0, stream>>>(Wv + (size_t)l*D_*D_,   wth+base+OV, wtl+base+OV, D_,  D_);
    transpose_split_kernel<<<dim3(16,16), 256, 0, stream>>>(Wo + (size_t)l*D_*D_,   wth+base+OO, wtl+base+OO, D_,  D_);
    transpose_split_kernel<<<dim3(64,16), 256, 0, stream>>>(W1 + (size_t)l*D_*DFF_, wth+base+O1, wtl+base+O1, D_,  DFF_);
    transpose_split_kernel<<<dim3(16,64), 256, 0, stream>>>(W2 + (size_t)l*DFF_*D_, wth+base+O2, wtl+base+O2, DFF_, D_);
  }

  init_x_kernel<<<4096, 256, 0, stream>>>(qe, pos, xh, xl);
  if (have_y)
    init_x_kernel<<<4096, 256, 0, stream>>>(ie, pos, yh, yl);

  for (int l = 0; l < L_; ++l) {
    size_t base = (size_t)l * LW;
    // q = k = x @ Wk + bk (kq_same), bf16 hi/lo out
    gemm_split3_kernel<<<dim3(4,128), 256, 0, stream>>>(xh, xl, nullptr, nullptr,
        wth+base+OK, wtl+base+OK, bk + (size_t)l*D_, qhb, qlb, BS_, D_, D_, 0);
    // v^T = ((ie + pos) @ Wv + bv)^T per batch
    if (have_y)   // fast DMA path: y precomputed, bit-identical values
      gemm_split3_kernel<<<dim3(4,128), 256, 0, stream>>>(yh, yl, nullptr, nullptr,
          wth+base+OV, wtl+base+OV, bv + (size_t)l*D_, vhb, vlb, BS_, D_, D_, 8);
    else          // fallback: fused fp32 y staging
      gemm_split3_kernel<<<dim3(4,128), 256, 0, stream>>>(nullptr, nullptr, ie, pos,
          wth+base+OV, wtl+base+OV, bv + (size_t)l*D_, vhb, vlb, BS_, D_, D_, 4|8);
    // sparse attention (1-D grid, XCD-affine decode inside)
    attn_kernel<<<dim3(32*H_*B_), 256, 0, stream>>>(qhb, qlb, vhb, vlb, ohb, olb);
    // out-proj -> t (hi/lo; overwrites q region, q is dead)
    gemm_split3_kernel<<<dim3(4,128), 256, 0, stream>>>(ohb, olb, nullptr, nullptr,
        wth+base+OO, wtl+base+OO, bo + (size_t)l*D_, thb, tlb, BS_, D_, D_, 0);
    // x = LN1(x + t)
    resid_ln_kernel<<<BS_/4, 256, 0, stream>>>(xh, xl, thb, tlb,
        ln1g + (size_t)l*D_, ln1b + (size_t)l*D_, xh, xl, nullptr);
    // FFN in two M=8192 chunks (hidden-hi aliases o region, out -> t region)
    for (int ch = 0; ch < 2; ++ch) {
      size_t ao = (size_t)ch*8192*D_;
      gemm_split3_kernel<<<dim3(16,64), 256, 0, stream>>>(xh + ao, xl + ao, nullptr, nullptr,
          wth+base+O1, wtl+base+O1, b1 + (size_t)l*DFF_, hhb, hlb, 8192, DFF_, D_, 1);
      gemm_split3_kernel<<<dim3(4,64), 256, 0, stream>>>(hhb, hlb, nullptr, nullptr,
          wth+base+O2, wtl+base+O2, b2 + (size_t)l*D_, thb + ao, tlb + ao, 8192, D_, DFF_, 0);
    }
    // x = LN2(x + t); final layer writes fp32 straight to d_out
    resid_ln_kernel<<<BS_/4, 256, 0, stream>>>(xh, xl, thb, tlb,
        ln2g + (size_t)l*D_, ln2b + (size_t)l*D_, xh, xl,
        (l == L_-1) ? xout : nullptr);
  }
}

// Round 5
// 1356.450 us; speedup vs baseline: 1.0562x; 1.0209x over previous
//
#include <hip/hip_runtime.h>

// ---------------------------------------------------------------------------
// SparseKT forward, MI355X gfx950. I/O dtype: fp32 (per reference).
// Numerics: fp32 tensors decomposed into hi/lo bf16 pairs (pseudo-fp32,
// rel err ~2^-17). GEMMs are split-3: C = Ah*Bh + Ah*Bl + Al*Bh (3 MFMAs).
// Softmax / exact top-5 / LayerNorm in fp32. Residual stream: hi/lo pairs.
// R9->R10: attn phase-2 ROW LOCKSTEP (pure ILP identity transform):
//   the wave's 4 rows run their UNCHANGED per-row algorithm (softmax + 5
//   sequential wave_max+ballot top-5 rounds) interleaved, so the 4 serial
//   cross-lane reduction chains overlap. Per-row arithmetic, shfl sequence,
//   and written values are bit-identical to R9 (rows are independent).
//   R2's failed rewrite bundled this with bitonic top-5 + depth-2 prefetch;
//   those remain OUT. Also: s_setprio(1) around GEMM MFMA cluster (T5; the
//   2-phase dbuf gives waves a staging/compute role-split).
// ---------------------------------------------------------------------------

#define L_   2
#define B_   32
#define S_   512
#define D_   512
#define H_   8
#define DH_  64
#define DFF_ 2048
#define BS_  (B_*S_)      // 16384

typedef __bf16 bfx8 __attribute__((ext_vector_type(8)));
typedef __bf16 bfx4 __attribute__((ext_vector_type(4)));
typedef float floatx4 __attribute__((ext_vector_type(4)));

__device__ __forceinline__ floatx4 mfma_bf16(bfx8 a, bfx8 b, floatx4 c) {
  return __builtin_amdgcn_mfma_f32_16x16x32_bf16(a, b, c, 0, 0, 0);
}

__device__ __forceinline__ float wave_sum(float v) {
  #pragma unroll
  for (int d = 32; d > 0; d >>= 1) v += __shfl_xor(v, d);
  return v;
}
__device__ __forceinline__ float wave_max(float v) {
  #pragma unroll
  for (int d = 32; d > 0; d >>= 1) v = fmaxf(v, __shfl_xor(v, d));
  return v;
}

// async global->LDS, 16 B per lane; LDS dest = wave-uniform base + lane*16
__device__ __forceinline__ void lds_load16(__bf16* lds, const __bf16* g) {
  __builtin_amdgcn_global_load_lds(
      (const __attribute__((address_space(1))) unsigned int*)g,
      (__attribute__((address_space(3))) unsigned int*)lds, 16, 0, 0);
}

// LDS chunk swizzle: logical 8-elem chunk q of row r stored at q ^ ((r>>1)&3)
__device__ __forceinline__ int swz(int row, int q) { return q ^ ((row >> 1) & 3); }

// ---------------------------------------------------------------------------
// init: x = emb + pos (fp32) -> bf16 hi/lo pair (used for both qe and ie)
// ---------------------------------------------------------------------------
__global__ void init_x_kernel(const float* __restrict__ qe, const float* __restrict__ pos,
                              __bf16* __restrict__ xh, __bf16* __restrict__ xl)
{
  size_t i = ((size_t)blockIdx.x * 256 + threadIdx.x) * 8;
  float4 a0 = *(const float4*)(qe + i);
  float4 a1 = *(const float4*)(qe + i + 4);
  size_t pi = i & (size_t)(S_*D_ - 1);
  float4 p0 = *(const float4*)(pos + pi);
  float4 p1 = *(const float4*)(pos + pi + 4);
  float v[8] = {a0.x+p0.x, a0.y+p0.y, a0.z+p0.z, a0.w+p0.w,
                a1.x+p1.x, a1.y+p1.y, a1.z+p1.z, a1.w+p1.w};
  bfx8 hv8, lv8;
  #pragma unroll
  for (int j = 0; j < 8; ++j) {
    __bf16 hv = (__bf16)v[j];
    hv8[j] = hv;
    lv8[j] = (__bf16)(v[j] - (float)hv);
  }
  *(bfx8*)(xh + i) = hv8;
  *(bfx8*)(xl + i) = lv8;
}

// ---------------------------------------------------------------------------
// weight transpose + hi/lo split:  W[K][N] fp32  ->  T{h,l}[N][K] bf16
// ---------------------------------------------------------------------------
__global__ void transpose_split_kernel(const float* __restrict__ Wsrc,
                                       __bf16* __restrict__ Th, __bf16* __restrict__ Tl,
                                       int K, int N)
{
  __shared__ float tile[32][33];
  int n0 = blockIdx.x * 32, k0 = blockIdx.y * 32;
  int tx = threadIdx.x & 31, ty8 = threadIdx.x >> 5;  // 0..7
  #pragma unroll
  for (int j = 0; j < 4; ++j) {
    int k = ty8 + j*8;
    tile[k][tx] = Wsrc[(size_t)(k0 + k) * N + n0 + tx];
  }
  __syncthreads();
  #pragma unroll
  for (int j = 0; j < 4; ++j) {
    int n = ty8 + j*8;
    float vv = tile[tx][n];           // = W[k0+tx][n0+n]
    size_t dst = (size_t)(n0 + n) * K + k0 + tx;
    __bf16 hv = (__bf16)vv;
    Th[dst] = hv;
    Tl[dst] = (__bf16)(vv - (float)hv);
  }
}

// ---------------------------------------------------------------------------
// split-3 GEMM: C[M,N] = A[M,K] @ Bt[N,K]^T + bias; output bf16 hi/lo pair.
// flags: 1 = relu, 4 = stage A from fp32 (Afa[m] + Afp[m mod S]) on the fly
//        8 = write transposed per-batch output C^T[b][n][s] (b = m/S, s = m%S)
// 128x128x32 tile, 4 waves (64x64 quadrant each, 16 MFMA tiles).
// 2-phase double-buffered: stage(t+1) issued before compute(t); one barrier
// per K-step (implicit vmcnt(0)+lgkmcnt(0) at __syncthreads drains staging).
// Fast path (no flag 4): wave w DMA-stages buffer-kind w via global_load_lds.
// LDS XOR-swizzled (swz) -> conflict-free ds_read_b128 fragments, no padding.
// ---------------------------------------------------------------------------
__global__ __launch_bounds__(256, 2)
void gemm_split3_kernel(const __bf16* __restrict__ Ah, const __bf16* __restrict__ Al,
                        const float* __restrict__ Afa, const float* __restrict__ Afp,
                        const __bf16* __restrict__ Bth, const __bf16* __restrict__ Btl,
                        const float* __restrict__ bias,
                        __bf16* __restrict__ Ch, __bf16* __restrict__ Cl,
                        int M, int N, int K, int flags)
{
  __shared__ __bf16 sAh[2*128*32], sAl[2*128*32], sBh[2*128*32], sBl[2*128*32];
  const int t = threadIdx.x;
  const int w = t >> 6, lane = t & 63;
  const int q4 = lane >> 4, r16 = lane & 15;
  const int m0 = blockIdx.y * 128, n0 = blockIdx.x * 128;
  const int wm = (w >> 1) * 64, wn = (w & 1) * 64;

  floatx4 acc[4][4];
  #pragma unroll
  for (int i = 0; i < 4; ++i)
    #pragma unroll
    for (int j = 0; j < 4; ++j)
      acc[i][j] = (floatx4){0.f, 0.f, 0.f, 0.f};

  // fast-path per-wave staging assignment: wave w stages buffer-kind w
  const __bf16* wsrc = (w == 0) ? Ah : (w == 1) ? Al : (w == 2) ? Bth : Btl;
  __bf16* wdst = (w == 0) ? sAh : (w == 1) ? sAl : (w == 2) ? sBh : sBl;
  const int rbase = (w < 2) ? m0 : n0;
  const int rl = lane >> 2;        // row within 16-row group
  const int cp = lane & 3;         // physical chunk this lane fills

  // manual-path (flags&4) mapping
  const int srow = t >> 2;          // 0..63
  const int sq   = t & 3;           // logical chunk

  auto stage = [&](int k0, int bo) {
    if (!(flags & 4)) {
      #pragma unroll
      for (int g = 0; g < 8; ++g) {
        int row = g*16 + rl;
        int qc = swz(row, cp);       // logical chunk landing at phys cp
        const __bf16* gp = wsrc + (size_t)(rbase + row) * K + k0 + qc*8;
        lds_load16(wdst + bo + g*512, gp);
      }
    } else {
      #pragma unroll
      for (int c = 0; c < 2; ++c) {
        int row = srow + c * 64;
        size_t ga = (size_t)(m0 + row) * K + k0 + sq*8;
        size_t gp = (size_t)((m0 + row) & (S_ - 1)) * K + k0 + sq*8;
        float4 e0 = *(const float4*)&Afa[ga];
        float4 e1 = *(const float4*)&Afa[ga + 4];
        float4 p0 = *(const float4*)&Afp[gp];
        float4 p1 = *(const float4*)&Afp[gp + 4];
        float sv[8] = {e0.x+p0.x, e0.y+p0.y, e0.z+p0.z, e0.w+p0.w,
                       e1.x+p1.x, e1.y+p1.y, e1.z+p1.z, e1.w+p1.w};
        bfx8 hv8, lv8;
        #pragma unroll
        for (int j = 0; j < 8; ++j) {
          __bf16 hv = (__bf16)sv[j];
          hv8[j] = hv;
          lv8[j] = (__bf16)(sv[j] - (float)hv);
        }
        int pc = swz(row, sq);
        *(bfx8*)&sAh[bo + row*32 + pc*8] = hv8;
        *(bfx8*)&sAl[bo + row*32 + pc*8] = lv8;
        size_t gb = (size_t)(n0 + row) * K + k0 + sq*8;
        *(bfx8*)&sBh[bo + row*32 + pc*8] = *(const bfx8*)&Bth[gb];
        *(bfx8*)&sBl[bo + row*32 + pc*8] = *(const bfx8*)&Btl[gb];
      }
    }
  };

  const int nk = K >> 5;
  stage(0, 0);
  __syncthreads();
  int bo = 0;
  for (int it = 0; it < nk; ++it) {
    if (it + 1 < nk) stage((it + 1) << 5, bo ^ 4096);  // overlap with compute
    bfx8 af[4][2], bfr[4][2];
    #pragma unroll
    for (int i = 0; i < 4; ++i) {
      int ar = wm + i*16 + r16;
      int sa = swz(ar, q4) * 8;
      af[i][0] = *(const bfx8*)&sAh[bo + ar*32 + sa];
      af[i][1] = *(const bfx8*)&sAl[bo + ar*32 + sa];
      int br = wn + i*16 + r16;
      int sb = swz(br, q4) * 8;
      bfr[i][0] = *(const bfx8*)&sBh[bo + br*32 + sb];
      bfr[i][1] = *(const bfx8*)&sBl[bo + br*32 + sb];
    }
    __builtin_amdgcn_s_setprio(1);
    #pragma unroll
    for (int i = 0; i < 4; ++i)
      #pragma unroll
      for (int j = 0; j < 4; ++j) {
        acc[i][j] = mfma_bf16(af[i][0], bfr[j][0], acc[i][j]);
        acc[i][j] = mfma_bf16(af[i][0], bfr[j][1], acc[i][j]);
        acc[i][j] = mfma_bf16(af[i][1], bfr[j][0], acc[i][j]);
      }
    __builtin_amdgcn_s_setprio(0);
    __syncthreads();     // drains staging DMA (vmcnt) + orders buffer reuse
    bo ^= 4096;
  }

  // epilogue (C/D layout: col = lane&15, row = (lane>>4)*4 + reg  [m89-verified])
  if (flags & 8) {
    // transposed per-batch write: C^T[b][n][s]; 4 regs = 4 consecutive s -> 8B store
    #pragma unroll
    for (int i = 0; i < 4; ++i)
      #pragma unroll
      for (int j = 0; j < 4; ++j) {
        int gn = n0 + wn + j*16 + r16;
        float bb = bias[gn];
        int gmb = m0 + wm + i*16 + q4*4;
        size_t co = ((size_t)(gmb >> 9) * N + gn) * S_ + (gmb & (S_ - 1));
        bfx4 hv4, lv4;
        #pragma unroll
        for (int r = 0; r < 4; ++r) {
          float val = acc[i][j][r] + bb;
          if (flags & 1) val = fmaxf(val, 0.f);
          __bf16 hv = (__bf16)val;
          hv4[r] = hv;
          lv4[r] = (__bf16)(val - (float)hv);
        }
        *(bfx4*)(Ch + co) = hv4;
        *(bfx4*)(Cl + co) = lv4;
      }
  } else {
    #pragma unroll
    for (int i = 0; i < 4; ++i)
      #pragma unroll
      for (int j = 0; j < 4; ++j) {
        int gn = n0 + wn + j*16 + r16;
        float bb = bias[gn];
        #pragma unroll
        for (int r = 0; r < 4; ++r) {
          int gm = m0 + wm + i*16 + q4*4 + r;
          float val = acc[i][j][r] + bb;
          if (flags & 1) val = fmaxf(val, 0.f);
          size_t co = (size_t)gm * N + gn;
          __bf16 hv = (__bf16)val;
          Ch[co] = hv;
          Cl[co] = (__bf16)(val - (float)hv);
        }
      }
  }
}

// ---------------------------------------------------------------------------
// attention: 1-D grid 8192, decoded so batch b == XCD (lin&7): K/V of a batch
// stay L2-resident on one XCD. Heavy q-tiles first within each XCD.
// NO K/V LDS staging (R9): fragments load directly global->register.
// phase 1: scores via MFMA (split-3), depth-1 register prefetch of K frags
// phase 2: softmax + exact top-5 re-softmax, 4 rows in LOCKSTEP (identical
//          per-row algorithm to R9; chains interleaved for ILP)
// phase 3: O^T = V^T @ P^T, V^T frags direct from global, depth-1 prefetch
// ---------------------------------------------------------------------------
__global__ __launch_bounds__(256, 4)
void attn_kernel(const __bf16* __restrict__ qh, const __bf16* __restrict__ ql,
                 const __bf16* __restrict__ vth, const __bf16* __restrict__ vtl,
                 __bf16* __restrict__ oh, __bf16* __restrict__ ol)
{
  constexpr int LSS = 516;                       // fp32 row stride (pad 4)
  __shared__ float Ssc[16*LSS];                  // 33 KB scores; P hi/lo after phase 2
  const int lin = blockIdx.x;
  const int xcd = lin & 7;
  const int ord = lin >> 3;                      // 0..1023 per xcd
  const int qt  = 31 - (ord & 31);               // heavy tiles first
  const int bh  = ord >> 5;                      // 0..31
  const int hd  = bh & 7;
  const int b   = ((bh >> 3) << 3) | xcd;        // b mod 8 == xcd
  const int t = threadIdx.x, w = t >> 6, lane = t & 63;
  const int q4 = lane >> 4, r16 = lane & 15;
  const int nkt = (qt >> 2) + 1;                 // 64-key tiles (causal)

  // Q fragments (A operand): rows qt*16+[0,16), cols hd*64+[0,64)
  bfx8 qf[2][2];
  {
    size_t base = ((size_t)(b*S_ + qt*16 + r16)) * D_ + hd*64;
    #pragma unroll
    for (int ks = 0; ks < 2; ++ks) {
      qf[ks][0] = *(const bfx8*)&qh[base + ks*32 + q4*8];
      qf[ks][1] = *(const bfx8*)&ql[base + ks*32 + q4*8];
    }
  }

  // fragment registers: current (c*) and prefetch (n*)
  bfx8 ch0, ch1, cl0, cl1, nh0, nh1, nl0, nl1;

  // ---- phase 1: scores; K B-frag row = kt*64 + w*16 + r16, col chunk q4*8 ----
  const size_t kstep = (size_t)64 * D_;
  const size_t kb0 = ((size_t)(b*S_ + w*16 + r16)) * D_ + hd*64 + q4*8;
  ch0 = *(const bfx8*)&qh[kb0];
  ch1 = *(const bfx8*)&qh[kb0 + 32];
  cl0 = *(const bfx8*)&ql[kb0];
  cl1 = *(const bfx8*)&ql[kb0 + 32];
  for (int kt = 0; kt < nkt; ++kt) {
    const bool more = (kt + 1 < nkt);
    if (more) {
      size_t nb = kb0 + (size_t)(kt + 1) * kstep;
      nh0 = *(const bfx8*)&qh[nb];
      nh1 = *(const bfx8*)&qh[nb + 32];
      nl0 = *(const bfx8*)&ql[nb];
      nl1 = *(const bfx8*)&ql[nb + 32];
    }
    floatx4 acc = (floatx4){0.f, 0.f, 0.f, 0.f};
    __builtin_amdgcn_s_setprio(1);
    acc = mfma_bf16(qf[0][0], ch0, acc);   // same order as staged version:
    acc = mfma_bf16(qf[0][0], cl0, acc);   // ks=0: h,l,h  then ks=1: h,l,h
    acc = mfma_bf16(qf[0][1], ch0, acc);
    acc = mfma_bf16(qf[1][0], ch1, acc);
    acc = mfma_bf16(qf[1][0], cl1, acc);
    acc = mfma_bf16(qf[1][1], ch1, acc);
    __builtin_amdgcn_s_setprio(0);
    int gcol = kt*64 + w*16 + r16;
    #pragma unroll
    for (int r = 0; r < 4; ++r) {
      int lrow = q4*4 + r;
      int grow = qt*16 + lrow;
      float sc = acc[r] * 0.125f;          // / sqrt(64)
      if (gcol >= grow) sc = -1e32f;       // strictly causal (tril k=-1)
      Ssc[lrow*LSS + gcol] = sc;
    }
    if (more) { ch0 = nh0; ch1 = nh1; cl0 = nl0; cl1 = nl1; }
  }
  __syncthreads();                         // phase-1 Ssc writes -> phase-2 reads

  // ---- phase 2: softmax + exact top-5 re-softmax; wave w owns rows w*4..+3,
  // 4 rows in LOCKSTEP (per-row algorithm identical to R9; rows independent).
  // final P written as bf16 hi/lo within the row's Ssc footprint:
  //   row byte base = lrow*LSS*4; hi at [key], lo at [512+key]  (2048B <= 2064B)
  {
    float p[4][8], mx[4], sm[4];
    #pragma unroll
    for (int rr = 0; rr < 4; ++rr) {
      const int lrow = w*4 + rr;
      float m = -3.0e38f;
      #pragma unroll
      for (int j = 0; j < 8; ++j) {
        p[rr][j] = (j < nkt) ? Ssc[lrow*LSS + j*64 + lane] : -1e32f;
        m = fmaxf(m, p[rr][j]);
      }
      mx[rr] = m;
    }
    #pragma unroll
    for (int d = 32; d > 0; d >>= 1) {
      #pragma unroll
      for (int rr = 0; rr < 4; ++rr) mx[rr] = fmaxf(mx[rr], __shfl_xor(mx[rr], d));
    }
    #pragma unroll
    for (int rr = 0; rr < 4; ++rr) {
      float s = 0.f;
      #pragma unroll
      for (int j = 0; j < 8; ++j) { p[rr][j] = __expf(p[rr][j] - mx[rr]); s += p[rr][j]; }
      sm[rr] = s;
    }
    #pragma unroll
    for (int d = 32; d > 0; d >>= 1) {
      #pragma unroll
      for (int rr = 0; rr < 4; ++rr) sm[rr] += __shfl_xor(sm[rr], d);
    }
    #pragma unroll
    for (int rr = 0; rr < 4; ++rr) {
      float inv = 1.0f / sm[rr];
      #pragma unroll
      for (int j = 0; j < 8; ++j) p[rr][j] *= inv;   // masked j: exp -> 0
    }

    // exact 5th order statistic (with duplicates, matching lax.top_k):
    // 5 sequential rounds, the wave's 4 rows interleaved per round.
    unsigned rm[4] = {0u, 0u, 0u, 0u};
    float pmax[4], thr[4];
    for (int it = 0; it < 5; ++it) {
      float loc[4]; int locj[4];
      #pragma unroll
      for (int rr = 0; rr < 4; ++rr) {
        loc[rr] = -1.f; locj[rr] = 0;
        #pragma unroll
        for (int j = 0; j < 8; ++j)
          if (!((rm[rr] >> j) & 1u) && p[rr][j] > loc[rr]) { loc[rr] = p[rr][j]; locj[rr] = j; }
      }
      float wm4[4] = {loc[0], loc[1], loc[2], loc[3]};
      #pragma unroll
      for (int d = 32; d > 0; d >>= 1) {
        #pragma unroll
        for (int rr = 0; rr < 4; ++rr) wm4[rr] = fmaxf(wm4[rr], __shfl_xor(wm4[rr], d));
      }
      #pragma unroll
      for (int rr = 0; rr < 4; ++rr) {
        if (it == 0) pmax[rr] = wm4[rr];
        thr[rr] = wm4[rr];
        unsigned long long ball = __ballot(loc[rr] == wm4[rr]);
        int first = (int)__builtin_ctzll(ball);          // remove one instance
        if (lane == first) rm[rr] |= 1u << locj[rr];
      }
    }

    // sparse re-softmax (grow > 5 rows only; grow is wave-uniform per rr).
    // overwrites p[rr] in place so no extra register array is needed.
    float s2[4];
    #pragma unroll
    for (int rr = 0; rr < 4; ++rr) {
      const int grow = qt*16 + w*4 + rr;               // wave-uniform
      if (grow > 5) {
        float s = 0.f;
        #pragma unroll
        for (int j = 0; j < 8; ++j) {
          float vv = (p[rr][j] - thr[rr] >= 0.f) ? __expf(p[rr][j] - pmax[rr]) : 0.f;
          p[rr][j] = vv; s += vv;
        }
        s2[rr] = s;
      } else {
        s2[rr] = 1.f;                                  // unused; keeps inv finite
      }
    }
    #pragma unroll
    for (int d = 32; d > 0; d >>= 1) {
      #pragma unroll
      for (int rr = 0; rr < 4; ++rr) s2[rr] += __shfl_xor(s2[rr], d);
    }

    #pragma unroll
    for (int rr = 0; rr < 4; ++rr) {
      const int lrow = w*4 + rr, grow = qt*16 + lrow;  // wave-uniform
      const float inv2 = 1.0f / s2[rr];
      __bf16* Prow = (__bf16*)&Ssc[lrow*LSS];
      #pragma unroll
      for (int j = 0; j < 8; ++j)
        if (j < nkt) {
          float f = (grow == 0) ? 0.f
                  : (grow <= 5) ? p[rr][j]
                  : p[rr][j] * inv2;
          int key = j*64 + lane;
          __bf16 hv = (__bf16)f;
          Prow[key]       = hv;
          Prow[512 + key] = (__bf16)(f - (float)hv);
        }
    }
  }
  __syncthreads();                         // phase-2 P writes -> phase-3 reads

  // ---- phase 3: O^T = V^T @ P^T; V^T frag row = hd*64 + w*16 + r16 (dh),
  //      cols = vt*64 + chunk (keys), direct from global ----
  const size_t vb0 = ((size_t)(b*D_ + hd*64 + w*16 + r16)) * S_ + q4*8;
  ch0 = *(const bfx8*)&vth[vb0];
  ch1 = *(const bfx8*)&vth[vb0 + 32];
  cl0 = *(const bfx8*)&vtl[vb0];
  cl1 = *(const bfx8*)&vtl[vb0 + 32];
  floatx4 oacc = (floatx4){0.f, 0.f, 0.f, 0.f};
  const __bf16* Pr = (const __bf16*)&Ssc[r16*LSS];
  for (int vt = 0; vt < nkt; ++vt) {
    const bool more = (vt + 1 < nkt);
    if (more) {
      size_t nb = vb0 + (size_t)(vt + 1) * 64;
      nh0 = *(const bfx8*)&vth[nb];
      nh1 = *(const bfx8*)&vth[nb + 32];
      nl0 = *(const bfx8*)&vtl[nb];
      nl1 = *(const bfx8*)&vtl[nb + 32];
    }
    bfx8 ph0 = *(const bfx8*)&Pr[vt*64 + q4*8];
    bfx8 pl0 = *(const bfx8*)&Pr[512 + vt*64 + q4*8];
    bfx8 ph1 = *(const bfx8*)&Pr[vt*64 + 32 + q4*8];
    bfx8 pl1 = *(const bfx8*)&Pr[512 + vt*64 + 32 + q4*8];
    __builtin_amdgcn_s_setprio(1);
    oacc = mfma_bf16(ch0, ph0, oacc);      // same order: ks=0 h,l,h; ks=1 h,l,h
    oacc = mfma_bf16(ch0, pl0, oacc);
    oacc = mfma_bf16(cl0, ph0, oacc);
    oacc = mfma_bf16(ch1, ph1, oacc);
    oacc = mfma_bf16(ch1, pl1, oacc);
    oacc = mfma_bf16(cl1, ph1, oacc);
    __builtin_amdgcn_s_setprio(0);
    if (more) { ch0 = nh0; ch1 = nh1; cl0 = nl0; cl1 = nl1; }
  }
  // D^T layout: col(lane&15) = q_local, row(q4*4+r) = dh_local in chunk w*16
  #pragma unroll
  for (int r = 0; r < 4; ++r) {
    int grow = qt*16 + r16;
    int dh  = w*16 + q4*4 + r;
    size_t off = ((size_t)(b*S_ + grow)) * D_ + hd*64 + dh;
    float val = oacc[r];
    __bf16 hv = (__bf16)val;
    oh[off] = hv;
    ol[off] = (__bf16)(val - (float)hv);
  }
}

// ---------------------------------------------------------------------------
// residual + LayerNorm (fp32): x = LN(xh+xl + th+tl); writes bf16 hi/lo pair
// and (if fout) the exact fp32 result. 1 wave/row, 4 rows/block.
// ---------------------------------------------------------------------------
__global__ void resid_ln_kernel(const __bf16* __restrict__ xhin, const __bf16* __restrict__ xlin,
                                const __bf16* __restrict__ thin, const __bf16* __restrict__ tlin,
                                const float* __restrict__ g, const float* __restrict__ bb,
                                __bf16* __restrict__ xh, __bf16* __restrict__ xl,
                                float* __restrict__ fout)
{
  int row = blockIdx.x * 4 + (threadIdx.x >> 6);
  int lane = threadIdx.x & 63;
  size_t base = (size_t)row * D_ + lane * 8;
  bfx8 h8 = *(const bfx8*)(xhin + base);
  bfx8 l8 = *(const bfx8*)(xlin + base);
  bfx8 th8 = *(const bfx8*)(thin + base);
  bfx8 tl8 = *(const bfx8*)(tlin + base);
  float v[8];
  #pragma unroll
  for (int j = 0; j < 8; ++j)
    v[j] = ((float)h8[j] + (float)l8[j]) + ((float)th8[j] + (float)tl8[j]);
  float s = 0.f;
  #pragma unroll
  for (int j = 0; j < 8; ++j) s += v[j];
  s = wave_sum(s);
  float mean = s * (1.0f/512.0f);
  float var = 0.f;
  #pragma unroll
  for (int j = 0; j < 8; ++j) { float d = v[j] - mean; var += d*d; }
  var = wave_sum(var) * (1.0f/512.0f);
  float rs = 1.0f / sqrtf(var + 1e-5f);
  float4 g0 = *(const float4*)(g + lane*8);
  float4 g1 = *(const float4*)(g + lane*8 + 4);
  float4 b0 = *(const float4*)(bb + lane*8);
  float4 b1 = *(const float4*)(bb + lane*8 + 4);
  float gg[8]  = {g0.x,g0.y,g0.z,g0.w,g1.x,g1.y,g1.z,g1.w};
  float bbv[8] = {b0.x,b0.y,b0.z,b0.w,b1.x,b1.y,b1.z,b1.w};
  float o[8];
  #pragma unroll
  for (int j = 0; j < 8; ++j) o[j] = (v[j] - mean) * rs * gg[j] + bbv[j];
  bfx8 hv8, lv8;
  #pragma unroll
  for (int j = 0; j < 8; ++j) {
    __bf16 hv = (__bf16)o[j];
    hv8[j] = hv;
    lv8[j] = (__bf16)(o[j] - (float)hv);
  }
  *(bfx8*)(xh + base) = hv8;
  *(bfx8*)(xl + base) = lv8;
  if (fout) {
    *(float4*)(fout + base)     = make_float4(o[0],o[1],o[2],o[3]);
    *(float4*)(fout + base + 4) = make_float4(o[4],o[5],o[6],o[7]);
  }
}

// ---------------------------------------------------------------------------
extern "C" void kernel_launch(void* const* d_in, const int* in_sizes, int n_in,
                              void* d_out, int out_size, void* d_ws, size_t ws_size,
                              hipStream_t stream)
{
  const float* qe   = (const float*)d_in[0];
  const float* ie   = (const float*)d_in[1];
  const float* pos  = (const float*)d_in[2];
  const float* Wk   = (const float*)d_in[3];
  const float* bk   = (const float*)d_in[4];
  const float* Wv   = (const float*)d_in[5];
  const float* bv   = (const float*)d_in[6];
  const float* Wo   = (const float*)d_in[7];
  const float* bo   = (const float*)d_in[8];
  const float* ln1g = (const float*)d_in[9];
  const float* ln1b = (const float*)d_in[10];
  const float* W1   = (const float*)d_in[11];
  const float* b1   = (const float*)d_in[12];
  const float* W2   = (const float*)d_in[13];
  const float* b2   = (const float*)d_in[14];
  const float* ln2g = (const float*)d_in[15];
  const float* ln2b = (const float*)d_in[16];

  char* wsp = (char*)d_ws;
  size_t off = 0;
  auto alloc = [&](size_t bytes) -> void* {
    void* p = wsp + off;
    off += (bytes + 255) & ~(size_t)255;
    return p;
  };
  const size_t NB = (size_t)BS_ * D_ * sizeof(__bf16);   // 16 MB per bf16 activation
  __bf16* xh  = (__bf16*)alloc(NB);
  __bf16* xl  = (__bf16*)alloc(NB);
  // q region aliases t (attn-out-proj / FFN2 result): q dead once out-proj runs
  char*   qt_ = (char*)  alloc(2*NB);
  __bf16* qhb = (__bf16*)qt_;
  __bf16* qlb = (__bf16*)(qt_ + NB);
  __bf16* thb = (__bf16*)qt_;
  __bf16* tlb = (__bf16*)(qt_ + NB);
  __bf16* vhb = (__bf16*)alloc(NB);       // V^T hi ([b][n][s])
  __bf16* vlb = (__bf16*)alloc(NB);       // V^T lo
  // o region (2*NB) aliases FFN hidden-hi (M=8192: 8192*2048*2B = 32MB = 2*NB)
  char*   oh_ = (char*) alloc(2*NB);
  __bf16* ohb = (__bf16*)oh_;
  __bf16* olb = (__bf16*)(oh_ + NB);
  __bf16* hhb = (__bf16*)oh_;
  __bf16* hlb = (__bf16*)alloc(2*NB);      // hidden-lo, 32 MB
  const size_t LW = 3*(size_t)D_*D_ + 2*(size_t)D_*DFF_;   // elems / layer
  __bf16* wth = (__bf16*)alloc(2*LW*sizeof(__bf16));
  __bf16* wtl = (__bf16*)alloc(2*LW*sizeof(__bf16));
  // y = ie + pos as bf16 hi/lo (allocated LAST; used only if ws fits)
  __bf16* yh = (__bf16*)alloc(NB);
  __bf16* yl = (__bf16*)alloc(NB);
  const bool have_y = (off <= ws_size);
  float*  xout = (float*)d_out;
  // total ws usage ~216 MB with y, ~184 MB without

  const size_t OK = 0, OV = (size_t)D_*D_, OO = 2*(size_t)D_*D_;
  const size_t O1 = 3*(size_t)D_*D_, O2 = 3*(size_t)D_*D_ + (size_t)D_*DFF_;

  // weight transposes + splits (recomputed each call; graph-capture safe)
  for (int l = 0; l < L_; ++l) {
    size_t base = (size_t)l * LW;
    transpose_split_kernel<<<dim3(16,16), 256, 0, stream>>>(Wk + (size_t)l*D_*D_,   wth+base+OK, wtl+base+OK, D_,  D_);
    transpose_split_kernel<<<dim3(16,16), 256, 0, stream>>>(Wv + (size_t)l*D_*D_,   wth+base+OV, wtl+base+OV, D_,  D_);
    transpose_split_kernel<<<dim3(16,16), 256, 0, stream>>>(Wo + (size_t)l*D_*D_,   wth+base+OO, wtl+base+OO, D_,  D_);
    transpose_split_kernel<<<dim3(64,16), 256, 0, stream>>>(W1 + (size_t)l*D_*DFF_, wth+base+O1, wtl+base+O1, D_,  DFF_);
    transpose_split_kernel<<<dim3(16,64), 256, 0, stream>>>(W2 + (size_t)l*DFF_*D_, wth+base+O2, wtl+base+O2, DFF_, D_);
  }

  init_x_kernel<<<4096, 256, 0, stream>>>(qe, pos, xh, xl);
  if (have_y)
    init_x_kernel<<<4096, 256, 0, stream>>>(ie, pos, yh, yl);

  for (int l = 0; l < L_; ++l) {
    size_t base = (size_t)l * LW;
    // q = k = x @ Wk + bk (kq_same), bf16 hi/lo out
    gemm_split3_kernel<<<dim3(4,128), 256, 0, stream>>>(xh, xl, nullptr, nullptr,
        wth+base+OK, wtl+base+OK, bk + (size_t)l*D_, qhb, qlb, BS_, D_, D_, 0);
    // v^T = ((ie + pos) @ Wv + bv)^T per batch
    if (have_y)   // fast DMA path: y precomputed, bit-identical values
      gemm_split3_kernel<<<dim3(4,128), 256, 0, stream>>>(yh, yl, nullptr, nullptr,
          wth+base+OV, wtl+base+OV, bv + (size_t)l*D_, vhb, vlb, BS_, D_, D_, 8);
    else          // fallback: fused fp32 y staging
      gemm_split3_kernel<<<dim3(4,128), 256, 0, stream>>>(nullptr, nullptr, ie, pos,
          wth+base+OV, wtl+base+OV, bv + (size_t)l*D_, vhb, vlb, BS_, D_, D_, 4|8);
    // sparse attention (1-D grid, XCD-affine decode inside)
    attn_kernel<<<dim3(32*H_*B_), 256, 0, stream>>>(qhb, qlb, vhb, vlb, ohb, olb);
    // out-proj -> t (hi/lo; overwrites q region, q is dead)
    gemm_split3_kernel<<<dim3(4,128), 256, 0, stream>>>(ohb, olb, nullptr, nullptr,
        wth+base+OO, wtl+base+OO, bo + (size_t)l*D_, thb, tlb, BS_, D_, D_, 0);
    // x = LN1(x + t)
    resid_ln_kernel<<<BS_/4, 256, 0, stream>>>(xh, xl, thb, tlb,
        ln1g + (size_t)l*D_, ln1b + (size_t)l*D_, xh, xl, nullptr);
    // FFN in two M=8192 chunks (hidden-hi aliases o region, out -> t region)
    for (int ch = 0; ch < 2; ++ch) {
      size_t ao = (size_t)ch*8192*D_;
      gemm_split3_kernel<<<dim3(16,64), 256, 0, stream>>>(xh + ao, xl + ao, nullptr, nullptr,
          wth+base+O1, wtl+base+O1, b1 + (size_t)l*DFF_, hhb, hlb, 8192, DFF_, D_, 1);
      gemm_split3_kernel<<<dim3(4,64), 256, 0, stream>>>(hhb, hlb, nullptr, nullptr,
          wth+base+O2, wtl+base+O2, b2 + (size_t)l*D_, thb + ao, tlb + ao, 8192, D_, DFF_, 0);
    }
    // x = LN2(x + t); final layer writes fp32 straight to d_out
    resid_ln_kernel<<<BS_/4, 256, 0, stream>>>(xh, xl, thb, tlb,
        ln2g + (size_t)l*D_, ln2b + (size_t)l*D_, xh, xl,
        (l == L_-1) ? xout : nullptr);
  }
}

// Round 6
// 1268.239 us; speedup vs baseline: 1.1296x; 1.0696x over previous
//
#include <hip/hip_runtime.h>

// ---------------------------------------------------------------------------
// SparseKT forward, MI355X gfx950. I/O dtype: fp32 (per reference).
// Numerics: fp32 tensors decomposed into hi/lo bf16 pairs (pseudo-fp32,
// rel err ~2^-17). GEMMs are split-3: C = Ah*Bh + Ah*Bl + Al*Bh (3 MFMAs).
// Softmax / exact top-5 / LayerNorm in fp32. Residual stream: hi/lo pairs.
// R10->R11: attn phase-3 SPARSE GATHER-PV. After top-5, P has ~5 nonzeros
// per row (survivor set == {p_final > 0}: rows>5 keep top-5, rows<=5 have
// <=grow<=5 live keys, row 0 all-zero). The dense MFMA PV sweep was ~99%
// multiplies-by-zero. New phase 3: per row, ballot-mask the survivors
// (wave-uniform u64 masks), gather the ~5 V rows (natural [b][s][d] layout,
// coalesced 128B reads), accumulate O[dh=lane] in exact fp32 FMAs.
// Deletes: all PV MFMAs, P bf16-pair conversion, V^T layout+prefetch, and
// the phase2->phase3 barrier (rows are wave-private). PV numerics improve
// (exact fp32 p). v-GEMM reverts to natural-layout output (flags=0).
// ---------------------------------------------------------------------------

#define L_   2
#define B_   32
#define S_   512
#define D_   512
#define H_   8
#define DH_  64
#define DFF_ 2048
#define BS_  (B_*S_)      // 16384

typedef __bf16 bfx8 __attribute__((ext_vector_type(8)));
typedef __bf16 bfx4 __attribute__((ext_vector_type(4)));
typedef float floatx4 __attribute__((ext_vector_type(4)));

__device__ __forceinline__ floatx4 mfma_bf16(bfx8 a, bfx8 b, floatx4 c) {
  return __builtin_amdgcn_mfma_f32_16x16x32_bf16(a, b, c, 0, 0, 0);
}

__device__ __forceinline__ float wave_sum(float v) {
  #pragma unroll
  for (int d = 32; d > 0; d >>= 1) v += __shfl_xor(v, d);
  return v;
}
__device__ __forceinline__ float wave_max(float v) {
  #pragma unroll
  for (int d = 32; d > 0; d >>= 1) v = fmaxf(v, __shfl_xor(v, d));
  return v;
}

// async global->LDS, 16 B per lane; LDS dest = wave-uniform base + lane*16
__device__ __forceinline__ void lds_load16(__bf16* lds, const __bf16* g) {
  __builtin_amdgcn_global_load_lds(
      (const __attribute__((address_space(1))) unsigned int*)g,
      (__attribute__((address_space(3))) unsigned int*)lds, 16, 0, 0);
}

// LDS chunk swizzle: logical 8-elem chunk q of row r stored at q ^ ((r>>1)&3)
__device__ __forceinline__ int swz(int row, int q) { return q ^ ((row >> 1) & 3); }

// ---------------------------------------------------------------------------
// init: x = emb + pos (fp32) -> bf16 hi/lo pair (used for both qe and ie)
// ---------------------------------------------------------------------------
__global__ void init_x_kernel(const float* __restrict__ qe, const float* __restrict__ pos,
                              __bf16* __restrict__ xh, __bf16* __restrict__ xl)
{
  size_t i = ((size_t)blockIdx.x * 256 + threadIdx.x) * 8;
  float4 a0 = *(const float4*)(qe + i);
  float4 a1 = *(const float4*)(qe + i + 4);
  size_t pi = i & (size_t)(S_*D_ - 1);
  float4 p0 = *(const float4*)(pos + pi);
  float4 p1 = *(const float4*)(pos + pi + 4);
  float v[8] = {a0.x+p0.x, a0.y+p0.y, a0.z+p0.z, a0.w+p0.w,
                a1.x+p1.x, a1.y+p1.y, a1.z+p1.z, a1.w+p1.w};
  bfx8 hv8, lv8;
  #pragma unroll
  for (int j = 0; j < 8; ++j) {
    __bf16 hv = (__bf16)v[j];
    hv8[j] = hv;
    lv8[j] = (__bf16)(v[j] - (float)hv);
  }
  *(bfx8*)(xh + i) = hv8;
  *(bfx8*)(xl + i) = lv8;
}

// ---------------------------------------------------------------------------
// weight transpose + hi/lo split:  W[K][N] fp32  ->  T{h,l}[N][K] bf16
// ---------------------------------------------------------------------------
__global__ void transpose_split_kernel(const float* __restrict__ Wsrc,
                                       __bf16* __restrict__ Th, __bf16* __restrict__ Tl,
                                       int K, int N)
{
  __shared__ float tile[32][33];
  int n0 = blockIdx.x * 32, k0 = blockIdx.y * 32;
  int tx = threadIdx.x & 31, ty8 = threadIdx.x >> 5;  // 0..7
  #pragma unroll
  for (int j = 0; j < 4; ++j) {
    int k = ty8 + j*8;
    tile[k][tx] = Wsrc[(size_t)(k0 + k) * N + n0 + tx];
  }
  __syncthreads();
  #pragma unroll
  for (int j = 0; j < 4; ++j) {
    int n = ty8 + j*8;
    float vv = tile[tx][n];           // = W[k0+tx][n0+n]
    size_t dst = (size_t)(n0 + n) * K + k0 + tx;
    __bf16 hv = (__bf16)vv;
    Th[dst] = hv;
    Tl[dst] = (__bf16)(vv - (float)hv);
  }
}

// ---------------------------------------------------------------------------
// split-3 GEMM: C[M,N] = A[M,K] @ Bt[N,K]^T + bias; output bf16 hi/lo pair.
// flags: 1 = relu, 4 = stage A from fp32 (Afa[m] + Afp[m mod S]) on the fly
//        8 = write transposed per-batch output C^T[b][n][s] (b = m/S, s = m%S)
// 128x128x32 tile, 4 waves (64x64 quadrant each, 16 MFMA tiles).
// 2-phase double-buffered: stage(t+1) issued before compute(t); one barrier
// per K-step (implicit vmcnt(0)+lgkmcnt(0) at __syncthreads drains staging).
// Fast path (no flag 4): wave w DMA-stages buffer-kind w via global_load_lds.
// LDS XOR-swizzled (swz) -> conflict-free ds_read_b128 fragments, no padding.
// ---------------------------------------------------------------------------
__global__ __launch_bounds__(256, 2)
void gemm_split3_kernel(const __bf16* __restrict__ Ah, const __bf16* __restrict__ Al,
                        const float* __restrict__ Afa, const float* __restrict__ Afp,
                        const __bf16* __restrict__ Bth, const __bf16* __restrict__ Btl,
                        const float* __restrict__ bias,
                        __bf16* __restrict__ Ch, __bf16* __restrict__ Cl,
                        int M, int N, int K, int flags)
{
  __shared__ __bf16 sAh[2*128*32], sAl[2*128*32], sBh[2*128*32], sBl[2*128*32];
  const int t = threadIdx.x;
  const int w = t >> 6, lane = t & 63;
  const int q4 = lane >> 4, r16 = lane & 15;
  const int m0 = blockIdx.y * 128, n0 = blockIdx.x * 128;
  const int wm = (w >> 1) * 64, wn = (w & 1) * 64;

  floatx4 acc[4][4];
  #pragma unroll
  for (int i = 0; i < 4; ++i)
    #pragma unroll
    for (int j = 0; j < 4; ++j)
      acc[i][j] = (floatx4){0.f, 0.f, 0.f, 0.f};

  // fast-path per-wave staging assignment: wave w stages buffer-kind w
  const __bf16* wsrc = (w == 0) ? Ah : (w == 1) ? Al : (w == 2) ? Bth : Btl;
  __bf16* wdst = (w == 0) ? sAh : (w == 1) ? sAl : (w == 2) ? sBh : sBl;
  const int rbase = (w < 2) ? m0 : n0;
  const int rl = lane >> 2;        // row within 16-row group
  const int cp = lane & 3;         // physical chunk this lane fills

  // manual-path (flags&4) mapping
  const int srow = t >> 2;          // 0..63
  const int sq   = t & 3;           // logical chunk

  auto stage = [&](int k0, int bo) {
    if (!(flags & 4)) {
      #pragma unroll
      for (int g = 0; g < 8; ++g) {
        int row = g*16 + rl;
        int qc = swz(row, cp);       // logical chunk landing at phys cp
        const __bf16* gp = wsrc + (size_t)(rbase + row) * K + k0 + qc*8;
        lds_load16(wdst + bo + g*512, gp);
      }
    } else {
      #pragma unroll
      for (int c = 0; c < 2; ++c) {
        int row = srow + c * 64;
        size_t ga = (size_t)(m0 + row) * K + k0 + sq*8;
        size_t gp = (size_t)((m0 + row) & (S_ - 1)) * K + k0 + sq*8;
        float4 e0 = *(const float4*)&Afa[ga];
        float4 e1 = *(const float4*)&Afa[ga + 4];
        float4 p0 = *(const float4*)&Afp[gp];
        float4 p1 = *(const float4*)&Afp[gp + 4];
        float sv[8] = {e0.x+p0.x, e0.y+p0.y, e0.z+p0.z, e0.w+p0.w,
                       e1.x+p1.x, e1.y+p1.y, e1.z+p1.z, e1.w+p1.w};
        bfx8 hv8, lv8;
        #pragma unroll
        for (int j = 0; j < 8; ++j) {
          __bf16 hv = (__bf16)sv[j];
          hv8[j] = hv;
          lv8[j] = (__bf16)(sv[j] - (float)hv);
        }
        int pc = swz(row, sq);
        *(bfx8*)&sAh[bo + row*32 + pc*8] = hv8;
        *(bfx8*)&sAl[bo + row*32 + pc*8] = lv8;
        size_t gb = (size_t)(n0 + row) * K + k0 + sq*8;
        *(bfx8*)&sBh[bo + row*32 + pc*8] = *(const bfx8*)&Bth[gb];
        *(bfx8*)&sBl[bo + row*32 + pc*8] = *(const bfx8*)&Btl[gb];
      }
    }
  };

  const int nk = K >> 5;
  stage(0, 0);
  __syncthreads();
  int bo = 0;
  for (int it = 0; it < nk; ++it) {
    if (it + 1 < nk) stage((it + 1) << 5, bo ^ 4096);  // overlap with compute
    bfx8 af[4][2], bfr[4][2];
    #pragma unroll
    for (int i = 0; i < 4; ++i) {
      int ar = wm + i*16 + r16;
      int sa = swz(ar, q4) * 8;
      af[i][0] = *(const bfx8*)&sAh[bo + ar*32 + sa];
      af[i][1] = *(const bfx8*)&sAl[bo + ar*32 + sa];
      int br = wn + i*16 + r16;
      int sb = swz(br, q4) * 8;
      bfr[i][0] = *(const bfx8*)&sBh[bo + br*32 + sb];
      bfr[i][1] = *(const bfx8*)&sBl[bo + br*32 + sb];
    }
    __builtin_amdgcn_s_setprio(1);
    #pragma unroll
    for (int i = 0; i < 4; ++i)
      #pragma unroll
      for (int j = 0; j < 4; ++j) {
        acc[i][j] = mfma_bf16(af[i][0], bfr[j][0], acc[i][j]);
        acc[i][j] = mfma_bf16(af[i][0], bfr[j][1], acc[i][j]);
        acc[i][j] = mfma_bf16(af[i][1], bfr[j][0], acc[i][j]);
      }
    __builtin_amdgcn_s_setprio(0);
    __syncthreads();     // drains staging DMA (vmcnt) + orders buffer reuse
    bo ^= 4096;
  }

  // epilogue (C/D layout: col = lane&15, row = (lane>>4)*4 + reg  [m89-verified])
  if (flags & 8) {
    // transposed per-batch write: C^T[b][n][s]; 4 regs = 4 consecutive s -> 8B store
    #pragma unroll
    for (int i = 0; i < 4; ++i)
      #pragma unroll
      for (int j = 0; j < 4; ++j) {
        int gn = n0 + wn + j*16 + r16;
        float bb = bias[gn];
        int gmb = m0 + wm + i*16 + q4*4;
        size_t co = ((size_t)(gmb >> 9) * N + gn) * S_ + (gmb & (S_ - 1));
        bfx4 hv4, lv4;
        #pragma unroll
        for (int r = 0; r < 4; ++r) {
          float val = acc[i][j][r] + bb;
          if (flags & 1) val = fmaxf(val, 0.f);
          __bf16 hv = (__bf16)val;
          hv4[r] = hv;
          lv4[r] = (__bf16)(val - (float)hv);
        }
        *(bfx4*)(Ch + co) = hv4;
        *(bfx4*)(Cl + co) = lv4;
      }
  } else {
    #pragma unroll
    for (int i = 0; i < 4; ++i)
      #pragma unroll
      for (int j = 0; j < 4; ++j) {
        int gn = n0 + wn + j*16 + r16;
        float bb = bias[gn];
        #pragma unroll
        for (int r = 0; r < 4; ++r) {
          int gm = m0 + wm + i*16 + q4*4 + r;
          float val = acc[i][j][r] + bb;
          if (flags & 1) val = fmaxf(val, 0.f);
          size_t co = (size_t)gm * N + gn;
          __bf16 hv = (__bf16)val;
          Ch[co] = hv;
          Cl[co] = (__bf16)(val - (float)hv);
        }
      }
  }
}

// ---------------------------------------------------------------------------
// attention: 1-D grid 8192, decoded so batch b == XCD (lin&7): K/V of a batch
// stay L2-resident on one XCD. Heavy q-tiles first within each XCD.
// phase 1: scores via MFMA (split-3), K frags direct global->reg, depth-1
//          prefetch (unchanged from R10).
// phase 2: softmax + exact top-5 re-softmax, 4 rows lockstep (unchanged);
//          final normalized p written to Ssc in fp32; survivor masks via
//          ballot(p>0) -- survivor set is exactly {p_final > 0}.
// phase 3: SPARSE gather-PV: per row, iterate ~5 survivor keys, gather
//          V[b][key][hd*64+lane] (natural layout, coalesced), fp32 FMA.
//          No MFMA, no P conversion, no barrier (rows are wave-private).
// ---------------------------------------------------------------------------
__global__ __launch_bounds__(256, 4)
void attn_kernel(const __bf16* __restrict__ qh, const __bf16* __restrict__ ql,
                 const __bf16* __restrict__ vh, const __bf16* __restrict__ vl,
                 __bf16* __restrict__ oh, __bf16* __restrict__ ol)
{
  constexpr int LSS = 516;                       // fp32 row stride (pad 4)
  __shared__ float Ssc[16*LSS];                  // 33 KB scores; final p after phase 2
  const int lin = blockIdx.x;
  const int xcd = lin & 7;
  const int ord = lin >> 3;                      // 0..1023 per xcd
  const int qt  = 31 - (ord & 31);               // heavy tiles first
  const int bh  = ord >> 5;                      // 0..31
  const int hd  = bh & 7;
  const int b   = ((bh >> 3) << 3) | xcd;        // b mod 8 == xcd
  const int t = threadIdx.x, w = t >> 6, lane = t & 63;
  const int q4 = lane >> 4, r16 = lane & 15;
  const int nkt = (qt >> 2) + 1;                 // 64-key tiles (causal)

  // Q fragments (A operand): rows qt*16+[0,16), cols hd*64+[0,64)
  bfx8 qf[2][2];
  {
    size_t base = ((size_t)(b*S_ + qt*16 + r16)) * D_ + hd*64;
    #pragma unroll
    for (int ks = 0; ks < 2; ++ks) {
      qf[ks][0] = *(const bfx8*)&qh[base + ks*32 + q4*8];
      qf[ks][1] = *(const bfx8*)&ql[base + ks*32 + q4*8];
    }
  }

  // fragment registers: current (c*) and prefetch (n*)
  bfx8 ch0, ch1, cl0, cl1, nh0, nh1, nl0, nl1;

  // ---- phase 1: scores; K B-frag row = kt*64 + w*16 + r16, col chunk q4*8 ----
  const size_t kstep = (size_t)64 * D_;
  const size_t kb0 = ((size_t)(b*S_ + w*16 + r16)) * D_ + hd*64 + q4*8;
  ch0 = *(const bfx8*)&qh[kb0];
  ch1 = *(const bfx8*)&qh[kb0 + 32];
  cl0 = *(const bfx8*)&ql[kb0];
  cl1 = *(const bfx8*)&ql[kb0 + 32];
  for (int kt = 0; kt < nkt; ++kt) {
    const bool more = (kt + 1 < nkt);
    if (more) {
      size_t nb = kb0 + (size_t)(kt + 1) * kstep;
      nh0 = *(const bfx8*)&qh[nb];
      nh1 = *(const bfx8*)&qh[nb + 32];
      nl0 = *(const bfx8*)&ql[nb];
      nl1 = *(const bfx8*)&ql[nb + 32];
    }
    floatx4 acc = (floatx4){0.f, 0.f, 0.f, 0.f};
    __builtin_amdgcn_s_setprio(1);
    acc = mfma_bf16(qf[0][0], ch0, acc);   // ks=0: h,l,h  then ks=1: h,l,h
    acc = mfma_bf16(qf[0][0], cl0, acc);
    acc = mfma_bf16(qf[0][1], ch0, acc);
    acc = mfma_bf16(qf[1][0], ch1, acc);
    acc = mfma_bf16(qf[1][0], cl1, acc);
    acc = mfma_bf16(qf[1][1], ch1, acc);
    __builtin_amdgcn_s_setprio(0);
    int gcol = kt*64 + w*16 + r16;
    #pragma unroll
    for (int r = 0; r < 4; ++r) {
      int lrow = q4*4 + r;
      int grow = qt*16 + lrow;
      float sc = acc[r] * 0.125f;          // / sqrt(64)
      if (gcol >= grow) sc = -1e32f;       // strictly causal (tril k=-1)
      Ssc[lrow*LSS + gcol] = sc;
    }
    if (more) { ch0 = nh0; ch1 = nh1; cl0 = nl0; cl1 = nl1; }
  }
  __syncthreads();                         // phase-1 Ssc writes -> phase-2 reads

  // ---- phase 2: softmax + exact top-5 re-softmax; wave w owns rows w*4..+3,
  // 4 rows in LOCKSTEP (per-row algorithm identical to R10).
  {
    float p[4][8], mx[4], sm[4];
    #pragma unroll
    for (int rr = 0; rr < 4; ++rr) {
      const int lrow = w*4 + rr;
      float m = -3.0e38f;
      #pragma unroll
      for (int j = 0; j < 8; ++j) {
        p[rr][j] = (j < nkt) ? Ssc[lrow*LSS + j*64 + lane] : -1e32f;
        m = fmaxf(m, p[rr][j]);
      }
      mx[rr] = m;
    }
    #pragma unroll
    for (int d = 32; d > 0; d >>= 1) {
      #pragma unroll
      for (int rr = 0; rr < 4; ++rr) mx[rr] = fmaxf(mx[rr], __shfl_xor(mx[rr], d));
    }
    #pragma unroll
    for (int rr = 0; rr < 4; ++rr) {
      float s = 0.f;
      #pragma unroll
      for (int j = 0; j < 8; ++j) { p[rr][j] = __expf(p[rr][j] - mx[rr]); s += p[rr][j]; }
      sm[rr] = s;
    }
    #pragma unroll
    for (int d = 32; d > 0; d >>= 1) {
      #pragma unroll
      for (int rr = 0; rr < 4; ++rr) sm[rr] += __shfl_xor(sm[rr], d);
    }
    #pragma unroll
    for (int rr = 0; rr < 4; ++rr) {
      float inv = 1.0f / sm[rr];
      #pragma unroll
      for (int j = 0; j < 8; ++j) p[rr][j] *= inv;   // masked j: exp -> 0
    }

    // exact 5th order statistic (with duplicates, matching lax.top_k):
    // 5 sequential rounds, the wave's 4 rows interleaved per round.
    unsigned rm[4] = {0u, 0u, 0u, 0u};
    float pmax[4], thr[4];
    for (int it = 0; it < 5; ++it) {
      float loc[4]; int locj[4];
      #pragma unroll
      for (int rr = 0; rr < 4; ++rr) {
        loc[rr] = -1.f; locj[rr] = 0;
        #pragma unroll
        for (int j = 0; j < 8; ++j)
          if (!((rm[rr] >> j) & 1u) && p[rr][j] > loc[rr]) { loc[rr] = p[rr][j]; locj[rr] = j; }
      }
      float wm4[4] = {loc[0], loc[1], loc[2], loc[3]};
      #pragma unroll
      for (int d = 32; d > 0; d >>= 1) {
        #pragma unroll
        for (int rr = 0; rr < 4; ++rr) wm4[rr] = fmaxf(wm4[rr], __shfl_xor(wm4[rr], d));
      }
      #pragma unroll
      for (int rr = 0; rr < 4; ++rr) {
        if (it == 0) pmax[rr] = wm4[rr];
        thr[rr] = wm4[rr];
        unsigned long long ball = __ballot(loc[rr] == wm4[rr]);
        int first = (int)__builtin_ctzll(ball);          // remove one instance
        if (lane == first) rm[rr] |= 1u << locj[rr];
      }
    }

    // sparse re-softmax (grow > 5 rows only; grow is wave-uniform per rr).
    float s2[4];
    #pragma unroll
    for (int rr = 0; rr < 4; ++rr) {
      const int grow = qt*16 + w*4 + rr;               // wave-uniform
      if (grow > 5) {
        float s = 0.f;
        #pragma unroll
        for (int j = 0; j < 8; ++j) {
          float vv = (p[rr][j] - thr[rr] >= 0.f) ? __expf(p[rr][j] - pmax[rr]) : 0.f;
          p[rr][j] = vv; s += vv;
        }
        s2[rr] = s;
      } else {
        s2[rr] = 1.f;                                  // unused; keeps inv finite
      }
    }
    #pragma unroll
    for (int d = 32; d > 0; d >>= 1) {
      #pragma unroll
      for (int rr = 0; rr < 4; ++rr) s2[rr] += __shfl_xor(s2[rr], d);
    }

    // ---- finalize + SPARSE gather-PV, per row (wave-private; no barrier) ----
    const __bf16* vbh = vh + (size_t)b*S_*D_ + hd*64 + lane;   // V[b][key][hd*64+lane]
    const __bf16* vbl = vl + (size_t)b*S_*D_ + hd*64 + lane;
    #pragma unroll
    for (int rr = 0; rr < 4; ++rr) {
      const int lrow = w*4 + rr, grow = qt*16 + lrow;  // wave-uniform
      const float inv2 = 1.0f / s2[rr];
      float* Prow = &Ssc[lrow*LSS];
      // final normalized p (fp32) -> Ssc; survivor masks via ballot(p>0)
      unsigned long long msk[8];
      #pragma unroll
      for (int j = 0; j < 8; ++j) {
        float f = (grow == 0) ? 0.f
                : (grow <= 5) ? p[rr][j]
                : p[rr][j] * inv2;
        Prow[j*64 + lane] = f;
        msk[j] = __ballot(f > 0.f);
      }
      // gather: O[grow][hd*64+lane] = sum over survivors f_key * V[b][key][..]
      float oacc = 0.f;
      #pragma unroll
      for (int j = 0; j < 8; ++j) {
        unsigned long long m = msk[j];
        while (m) {
          int kk = (int)__builtin_ctzll(m); m &= m - 1;
          int key = j*64 + kk;
          float pv = Prow[j*64 + kk];                  // LDS broadcast read
          size_t vo = (size_t)key * D_;
          float vv = (float)vbh[vo] + (float)vbl[vo];  // coalesced 128B rows
          oacc = fmaf(pv, vv, oacc);
        }
      }
      size_t off = ((size_t)(b*S_ + grow)) * D_ + hd*64 + lane;
      __bf16 hv = (__bf16)oacc;
      oh[off] = hv;
      ol[off] = (__bf16)(oacc - (float)hv);
    }
  }
}

// ---------------------------------------------------------------------------
// residual + LayerNorm (fp32): x = LN(xh+xl + th+tl); writes bf16 hi/lo pair
// and (if fout) the exact fp32 result. 1 wave/row, 4 rows/block.
// ---------------------------------------------------------------------------
__global__ void resid_ln_kernel(const __bf16* __restrict__ xhin, const __bf16* __restrict__ xlin,
                                const __bf16* __restrict__ thin, const __bf16* __restrict__ tlin,
                                const float* __restrict__ g, const float* __restrict__ bb,
                                __bf16* __restrict__ xh, __bf16* __restrict__ xl,
                                float* __restrict__ fout)
{
  int row = blockIdx.x * 4 + (threadIdx.x >> 6);
  int lane = threadIdx.x & 63;
  size_t base = (size_t)row * D_ + lane * 8;
  bfx8 h8 = *(const bfx8*)(xhin + base);
  bfx8 l8 = *(const bfx8*)(xlin + base);
  bfx8 th8 = *(const bfx8*)(thin + base);
  bfx8 tl8 = *(const bfx8*)(tlin + base);
  float v[8];
  #pragma unroll
  for (int j = 0; j < 8; ++j)
    v[j] = ((float)h8[j] + (float)l8[j]) + ((float)th8[j] + (float)tl8[j]);
  float s = 0.f;
  #pragma unroll
  for (int j = 0; j < 8; ++j) s += v[j];
  s = wave_sum(s);
  float mean = s * (1.0f/512.0f);
  float var = 0.f;
  #pragma unroll
  for (int j = 0; j < 8; ++j) { float d = v[j] - mean; var += d*d; }
  var = wave_sum(var) * (1.0f/512.0f);
  float rs = 1.0f / sqrtf(var + 1e-5f);
  float4 g0 = *(const float4*)(g + lane*8);
  float4 g1 = *(const float4*)(g + lane*8 + 4);
  float4 b0 = *(const float4*)(bb + lane*8);
  float4 b1 = *(const float4*)(bb + lane*8 + 4);
  float gg[8]  = {g0.x,g0.y,g0.z,g0.w,g1.x,g1.y,g1.z,g1.w};
  float bbv[8] = {b0.x,b0.y,b0.z,b0.w,b1.x,b1.y,b1.z,b1.w};
  float o[8];
  #pragma unroll
  for (int j = 0; j < 8; ++j) o[j] = (v[j] - mean) * rs * gg[j] + bbv[j];
  bfx8 hv8, lv8;
  #pragma unroll
  for (int j = 0; j < 8; ++j) {
    __bf16 hv = (__bf16)o[j];
    hv8[j] = hv;
    lv8[j] = (__bf16)(o[j] - (float)hv);
  }
  *(bfx8*)(xh + base) = hv8;
  *(bfx8*)(xl + base) = lv8;
  if (fout) {
    *(float4*)(fout + base)     = make_float4(o[0],o[1],o[2],o[3]);
    *(float4*)(fout + base + 4) = make_float4(o[4],o[5],o[6],o[7]);
  }
}

// ---------------------------------------------------------------------------
extern "C" void kernel_launch(void* const* d_in, const int* in_sizes, int n_in,
                              void* d_out, int out_size, void* d_ws, size_t ws_size,
                              hipStream_t stream)
{
  const float* qe   = (const float*)d_in[0];
  const float* ie   = (const float*)d_in[1];
  const float* pos  = (const float*)d_in[2];
  const float* Wk   = (const float*)d_in[3];
  const float* bk   = (const float*)d_in[4];
  const float* Wv   = (const float*)d_in[5];
  const float* bv   = (const float*)d_in[6];
  const float* Wo   = (const float*)d_in[7];
  const float* bo   = (const float*)d_in[8];
  const float* ln1g = (const float*)d_in[9];
  const float* ln1b = (const float*)d_in[10];
  const float* W1   = (const float*)d_in[11];
  const float* b1   = (const float*)d_in[12];
  const float* W2   = (const float*)d_in[13];
  const float* b2   = (const float*)d_in[14];
  const float* ln2g = (const float*)d_in[15];
  const float* ln2b = (const float*)d_in[16];

  char* wsp = (char*)d_ws;
  size_t off = 0;
  auto alloc = [&](size_t bytes) -> void* {
    void* p = wsp + off;
    off += (bytes + 255) & ~(size_t)255;
    return p;
  };
  const size_t NB = (size_t)BS_ * D_ * sizeof(__bf16);   // 16 MB per bf16 activation
  __bf16* xh  = (__bf16*)alloc(NB);
  __bf16* xl  = (__bf16*)alloc(NB);
  // q region aliases t (attn-out-proj / FFN2 result): q dead once out-proj runs
  char*   qt_ = (char*)  alloc(2*NB);
  __bf16* qhb = (__bf16*)qt_;
  __bf16* qlb = (__bf16*)(qt_ + NB);
  __bf16* thb = (__bf16*)qt_;
  __bf16* tlb = (__bf16*)(qt_ + NB);
  __bf16* vhb = (__bf16*)alloc(NB);       // V hi ([b][s][d], natural layout)
  __bf16* vlb = (__bf16*)alloc(NB);       // V lo
  // o region (2*NB) aliases FFN hidden-hi (M=8192: 8192*2048*2B = 32MB = 2*NB)
  char*   oh_ = (char*) alloc(2*NB);
  __bf16* ohb = (__bf16*)oh_;
  __bf16* olb = (__bf16*)(oh_ + NB);
  __bf16* hhb = (__bf16*)oh_;
  __bf16* hlb = (__bf16*)alloc(2*NB);      // hidden-lo, 32 MB
  const size_t LW = 3*(size_t)D_*D_ + 2*(size_t)D_*DFF_;   // elems / layer
  __bf16* wth = (__bf16*)alloc(2*LW*sizeof(__bf16));
  __bf16* wtl = (__bf16*)alloc(2*LW*sizeof(__bf16));
  // y = ie + pos as bf16 hi/lo (allocated LAST; used only if ws fits)
  __bf16* yh = (__bf16*)alloc(NB);
  __bf16* yl = (__bf16*)alloc(NB);
  const bool have_y = (off <= ws_size);
  float*  xout = (float*)d_out;
  // total ws usage ~216 MB with y, ~184 MB without

  const size_t OK = 0, OV = (size_t)D_*D_, OO = 2*(size_t)D_*D_;
  const size_t O1 = 3*(size_t)D_*D_, O2 = 3*(size_t)D_*D_ + (size_t)D_*DFF_;

  // weight transposes + splits (recomputed each call; graph-capture safe)
  for (int l = 0; l < L_; ++l) {
    size_t base = (size_t)l * LW;
    transpose_split_kernel<<<dim3(16,16), 256, 0, stream>>>(Wk + (size_t)l*D_*D_,   wth+base+OK, wtl+base+OK, D_,  D_);
    transpose_split_kernel<<<dim3(16,16), 256, 0, stream>>>(Wv + (size_t)l*D_*D_,   wth+base+OV, wtl+base+OV, D_,  D_);
    transpose_split_kernel<<<dim3(16,16), 256, 0, stream>>>(Wo + (size_t)l*D_*D_,   wth+base+OO, wtl+base+OO, D_,  D_);
    transpose_split_kernel<<<dim3(64,16), 256, 0, stream>>>(W1 + (size_t)l*D_*DFF_, wth+base+O1, wtl+base+O1, D_,  DFF_);
    transpose_split_kernel<<<dim3(16,64), 256, 0, stream>>>(W2 + (size_t)l*DFF_*D_, wth+base+O2, wtl+base+O2, DFF_, D_);
  }

  init_x_kernel<<<4096, 256, 0, stream>>>(qe, pos, xh, xl);
  if (have_y)
    init_x_kernel<<<4096, 256, 0, stream>>>(ie, pos, yh, yl);

  for (int l = 0; l < L_; ++l) {
    size_t base = (size_t)l * LW;
    // q = k = x @ Wk + bk (kq_same), bf16 hi/lo out
    gemm_split3_kernel<<<dim3(4,128), 256, 0, stream>>>(xh, xl, nullptr, nullptr,
        wth+base+OK, wtl+base+OK, bk + (size_t)l*D_, qhb, qlb, BS_, D_, D_, 0);
    // v = (ie + pos) @ Wv + bv, natural [b][s][d] layout
    if (have_y)   // fast DMA path: y precomputed
      gemm_split3_kernel<<<dim3(4,128), 256, 0, stream>>>(yh, yl, nullptr, nullptr,
          wth+base+OV, wtl+base+OV, bv + (size_t)l*D_, vhb, vlb, BS_, D_, D_, 0);
    else          // fallback: fused fp32 y staging
      gemm_split3_kernel<<<dim3(4,128), 256, 0, stream>>>(nullptr, nullptr, ie, pos,
          wth+base+OV, wtl+base+OV, bv + (size_t)l*D_, vhb, vlb, BS_, D_, D_, 4);
    // sparse attention (1-D grid, XCD-affine decode inside)
    attn_kernel<<<dim3(32*H_*B_), 256, 0, stream>>>(qhb, qlb, vhb, vlb, ohb, olb);
    // out-proj -> t (hi/lo; overwrites q region, q is dead)
    gemm_split3_kernel<<<dim3(4,128), 256, 0, stream>>>(ohb, olb, nullptr, nullptr,
        wth+base+OO, wtl+base+OO, bo + (size_t)l*D_, thb, tlb, BS_, D_, D_, 0);
    // x = LN1(x + t)
    resid_ln_kernel<<<BS_/4, 256, 0, stream>>>(xh, xl, thb, tlb,
        ln1g + (size_t)l*D_, ln1b + (size_t)l*D_, xh, xl, nullptr);
    // FFN in two M=8192 chunks (hidden-hi aliases o region, out -> t region)
    for (int ch = 0; ch < 2; ++ch) {
      size_t ao = (size_t)ch*8192*D_;
      gemm_split3_kernel<<<dim3(16,64), 256, 0, stream>>>(xh + ao, xl + ao, nullptr, nullptr,
          wth+base+O1, wtl+base+O1, b1 + (size_t)l*DFF_, hhb, hlb, 8192, DFF_, D_, 1);
      gemm_split3_kernel<<<dim3(4,64), 256, 0, stream>>>(hhb, hlb, nullptr, nullptr,
          wth+base+O2, wtl+base+O2, b2 + (size_t)l*D_, thb + ao, tlb + ao, 8192, D_, DFF_, 0);
    }
    // x = LN2(x + t); final layer writes fp32 straight to d_out
    resid_ln_kernel<<<BS_/4, 256, 0, stream>>>(xh, xl, thb, tlb,
        ln2g + (size_t)l*D_, ln2b + (size_t)l*D_, xh, xl,
        (l == L_-1) ? xout : nullptr);
  }
}

// Round 7
// 1252.973 us; speedup vs baseline: 1.1434x; 1.0122x over previous
//
#include <hip/hip_runtime.h>

// ---------------------------------------------------------------------------
// SparseKT forward, MI355X gfx950. I/O dtype: fp32 (per reference).
// Numerics: fp32 tensors decomposed into hi/lo bf16 pairs (pseudo-fp32,
// rel err ~2^-17). GEMMs are split-3: C = Ah*Bh + Ah*Bl + Al*Bh (3 MFMAs).
// Softmax / exact top-5 / LayerNorm in fp32. Residual stream: hi/lo pairs.
// R11->R12: FFN OCCUPANCY FIX (bit-identical numerics). FFN2 ran as two
// M=8192 chunks with grid (4,64) = 256 blocks = 1 block/CU (4 waves/CU) on
// the longest K-loop (K=2048) -- half the machine idle. With full-size
// hidden buffers (128 MB hi+lo, ws_size-guarded), FFN runs un-chunked:
// FFN2 grid (4,128) = 512 blocks = 2 blocks/CU. Exact chunked fallback if
// ws is too small. attn/GEMM kernels unchanged from R11.
// ---------------------------------------------------------------------------

#define L_   2
#define B_   32
#define S_   512
#define D_   512
#define H_   8
#define DH_  64
#define DFF_ 2048
#define BS_  (B_*S_)      // 16384

typedef __bf16 bfx8 __attribute__((ext_vector_type(8)));
typedef __bf16 bfx4 __attribute__((ext_vector_type(4)));
typedef float floatx4 __attribute__((ext_vector_type(4)));

__device__ __forceinline__ floatx4 mfma_bf16(bfx8 a, bfx8 b, floatx4 c) {
  return __builtin_amdgcn_mfma_f32_16x16x32_bf16(a, b, c, 0, 0, 0);
}

__device__ __forceinline__ float wave_sum(float v) {
  #pragma unroll
  for (int d = 32; d > 0; d >>= 1) v += __shfl_xor(v, d);
  return v;
}
__device__ __forceinline__ float wave_max(float v) {
  #pragma unroll
  for (int d = 32; d > 0; d >>= 1) v = fmaxf(v, __shfl_xor(v, d));
  return v;
}

// async global->LDS, 16 B per lane; LDS dest = wave-uniform base + lane*16
__device__ __forceinline__ void lds_load16(__bf16* lds, const __bf16* g) {
  __builtin_amdgcn_global_load_lds(
      (const __attribute__((address_space(1))) unsigned int*)g,
      (__attribute__((address_space(3))) unsigned int*)lds, 16, 0, 0);
}

// LDS chunk swizzle: logical 8-elem chunk q of row r stored at q ^ ((r>>1)&3)
__device__ __forceinline__ int swz(int row, int q) { return q ^ ((row >> 1) & 3); }

// ---------------------------------------------------------------------------
// init: x = emb + pos (fp32) -> bf16 hi/lo pair (used for both qe and ie)
// ---------------------------------------------------------------------------
__global__ void init_x_kernel(const float* __restrict__ qe, const float* __restrict__ pos,
                              __bf16* __restrict__ xh, __bf16* __restrict__ xl)
{
  size_t i = ((size_t)blockIdx.x * 256 + threadIdx.x) * 8;
  float4 a0 = *(const float4*)(qe + i);
  float4 a1 = *(const float4*)(qe + i + 4);
  size_t pi = i & (size_t)(S_*D_ - 1);
  float4 p0 = *(const float4*)(pos + pi);
  float4 p1 = *(const float4*)(pos + pi + 4);
  float v[8] = {a0.x+p0.x, a0.y+p0.y, a0.z+p0.z, a0.w+p0.w,
                a1.x+p1.x, a1.y+p1.y, a1.z+p1.z, a1.w+p1.w};
  bfx8 hv8, lv8;
  #pragma unroll
  for (int j = 0; j < 8; ++j) {
    __bf16 hv = (__bf16)v[j];
    hv8[j] = hv;
    lv8[j] = (__bf16)(v[j] - (float)hv);
  }
  *(bfx8*)(xh + i) = hv8;
  *(bfx8*)(xl + i) = lv8;
}

// ---------------------------------------------------------------------------
// weight transpose + hi/lo split:  W[K][N] fp32  ->  T{h,l}[N][K] bf16
// ---------------------------------------------------------------------------
__global__ void transpose_split_kernel(const float* __restrict__ Wsrc,
                                       __bf16* __restrict__ Th, __bf16* __restrict__ Tl,
                                       int K, int N)
{
  __shared__ float tile[32][33];
  int n0 = blockIdx.x * 32, k0 = blockIdx.y * 32;
  int tx = threadIdx.x & 31, ty8 = threadIdx.x >> 5;  // 0..7
  #pragma unroll
  for (int j = 0; j < 4; ++j) {
    int k = ty8 + j*8;
    tile[k][tx] = Wsrc[(size_t)(k0 + k) * N + n0 + tx];
  }
  __syncthreads();
  #pragma unroll
  for (int j = 0; j < 4; ++j) {
    int n = ty8 + j*8;
    float vv = tile[tx][n];           // = W[k0+tx][n0+n]
    size_t dst = (size_t)(n0 + n) * K + k0 + tx;
    __bf16 hv = (__bf16)vv;
    Th[dst] = hv;
    Tl[dst] = (__bf16)(vv - (float)hv);
  }
}

// ---------------------------------------------------------------------------
// split-3 GEMM: C[M,N] = A[M,K] @ Bt[N,K]^T + bias; output bf16 hi/lo pair.
// flags: 1 = relu, 4 = stage A from fp32 (Afa[m] + Afp[m mod S]) on the fly
//        8 = write transposed per-batch output C^T[b][n][s] (b = m/S, s = m%S)
// 128x128x32 tile, 4 waves (64x64 quadrant each, 16 MFMA tiles).
// 2-phase double-buffered: stage(t+1) issued before compute(t); one barrier
// per K-step (implicit vmcnt(0)+lgkmcnt(0) at __syncthreads drains staging).
// Fast path (no flag 4): wave w DMA-stages buffer-kind w via global_load_lds.
// LDS XOR-swizzled (swz) -> conflict-free ds_read_b128 fragments, no padding.
// ---------------------------------------------------------------------------
__global__ __launch_bounds__(256, 2)
void gemm_split3_kernel(const __bf16* __restrict__ Ah, const __bf16* __restrict__ Al,
                        const float* __restrict__ Afa, const float* __restrict__ Afp,
                        const __bf16* __restrict__ Bth, const __bf16* __restrict__ Btl,
                        const float* __restrict__ bias,
                        __bf16* __restrict__ Ch, __bf16* __restrict__ Cl,
                        int M, int N, int K, int flags)
{
  __shared__ __bf16 sAh[2*128*32], sAl[2*128*32], sBh[2*128*32], sBl[2*128*32];
  const int t = threadIdx.x;
  const int w = t >> 6, lane = t & 63;
  const int q4 = lane >> 4, r16 = lane & 15;
  const int m0 = blockIdx.y * 128, n0 = blockIdx.x * 128;
  const int wm = (w >> 1) * 64, wn = (w & 1) * 64;

  floatx4 acc[4][4];
  #pragma unroll
  for (int i = 0; i < 4; ++i)
    #pragma unroll
    for (int j = 0; j < 4; ++j)
      acc[i][j] = (floatx4){0.f, 0.f, 0.f, 0.f};

  // fast-path per-wave staging assignment: wave w stages buffer-kind w
  const __bf16* wsrc = (w == 0) ? Ah : (w == 1) ? Al : (w == 2) ? Bth : Btl;
  __bf16* wdst = (w == 0) ? sAh : (w == 1) ? sAl : (w == 2) ? sBh : sBl;
  const int rbase = (w < 2) ? m0 : n0;
  const int rl = lane >> 2;        // row within 16-row group
  const int cp = lane & 3;         // physical chunk this lane fills

  // manual-path (flags&4) mapping
  const int srow = t >> 2;          // 0..63
  const int sq   = t & 3;           // logical chunk

  auto stage = [&](int k0, int bo) {
    if (!(flags & 4)) {
      #pragma unroll
      for (int g = 0; g < 8; ++g) {
        int row = g*16 + rl;
        int qc = swz(row, cp);       // logical chunk landing at phys cp
        const __bf16* gp = wsrc + (size_t)(rbase + row) * K + k0 + qc*8;
        lds_load16(wdst + bo + g*512, gp);
      }
    } else {
      #pragma unroll
      for (int c = 0; c < 2; ++c) {
        int row = srow + c * 64;
        size_t ga = (size_t)(m0 + row) * K + k0 + sq*8;
        size_t gp = (size_t)((m0 + row) & (S_ - 1)) * K + k0 + sq*8;
        float4 e0 = *(const float4*)&Afa[ga];
        float4 e1 = *(const float4*)&Afa[ga + 4];
        float4 p0 = *(const float4*)&Afp[gp];
        float4 p1 = *(const float4*)&Afp[gp + 4];
        float sv[8] = {e0.x+p0.x, e0.y+p0.y, e0.z+p0.z, e0.w+p0.w,
                       e1.x+p1.x, e1.y+p1.y, e1.z+p1.z, e1.w+p1.w};
        bfx8 hv8, lv8;
        #pragma unroll
        for (int j = 0; j < 8; ++j) {
          __bf16 hv = (__bf16)sv[j];
          hv8[j] = hv;
          lv8[j] = (__bf16)(sv[j] - (float)hv);
        }
        int pc = swz(row, sq);
        *(bfx8*)&sAh[bo + row*32 + pc*8] = hv8;
        *(bfx8*)&sAl[bo + row*32 + pc*8] = lv8;
        size_t gb = (size_t)(n0 + row) * K + k0 + sq*8;
        *(bfx8*)&sBh[bo + row*32 + pc*8] = *(const bfx8*)&Bth[gb];
        *(bfx8*)&sBl[bo + row*32 + pc*8] = *(const bfx8*)&Btl[gb];
      }
    }
  };

  const int nk = K >> 5;
  stage(0, 0);
  __syncthreads();
  int bo = 0;
  for (int it = 0; it < nk; ++it) {
    if (it + 1 < nk) stage((it + 1) << 5, bo ^ 4096);  // overlap with compute
    bfx8 af[4][2], bfr[4][2];
    #pragma unroll
    for (int i = 0; i < 4; ++i) {
      int ar = wm + i*16 + r16;
      int sa = swz(ar, q4) * 8;
      af[i][0] = *(const bfx8*)&sAh[bo + ar*32 + sa];
      af[i][1] = *(const bfx8*)&sAl[bo + ar*32 + sa];
      int br = wn + i*16 + r16;
      int sb = swz(br, q4) * 8;
      bfr[i][0] = *(const bfx8*)&sBh[bo + br*32 + sb];
      bfr[i][1] = *(const bfx8*)&sBl[bo + br*32 + sb];
    }
    __builtin_amdgcn_s_setprio(1);
    #pragma unroll
    for (int i = 0; i < 4; ++i)
      #pragma unroll
      for (int j = 0; j < 4; ++j) {
        acc[i][j] = mfma_bf16(af[i][0], bfr[j][0], acc[i][j]);
        acc[i][j] = mfma_bf16(af[i][0], bfr[j][1], acc[i][j]);
        acc[i][j] = mfma_bf16(af[i][1], bfr[j][0], acc[i][j]);
      }
    __builtin_amdgcn_s_setprio(0);
    __syncthreads();     // drains staging DMA (vmcnt) + orders buffer reuse
    bo ^= 4096;
  }

  // epilogue (C/D layout: col = lane&15, row = (lane>>4)*4 + reg  [m89-verified])
  if (flags & 8) {
    // transposed per-batch write: C^T[b][n][s]; 4 regs = 4 consecutive s -> 8B store
    #pragma unroll
    for (int i = 0; i < 4; ++i)
      #pragma unroll
      for (int j = 0; j < 4; ++j) {
        int gn = n0 + wn + j*16 + r16;
        float bb = bias[gn];
        int gmb = m0 + wm + i*16 + q4*4;
        size_t co = ((size_t)(gmb >> 9) * N + gn) * S_ + (gmb & (S_ - 1));
        bfx4 hv4, lv4;
        #pragma unroll
        for (int r = 0; r < 4; ++r) {
          float val = acc[i][j][r] + bb;
          if (flags & 1) val = fmaxf(val, 0.f);
          __bf16 hv = (__bf16)val;
          hv4[r] = hv;
          lv4[r] = (__bf16)(val - (float)hv);
        }
        *(bfx4*)(Ch + co) = hv4;
        *(bfx4*)(Cl + co) = lv4;
      }
  } else {
    #pragma unroll
    for (int i = 0; i < 4; ++i)
      #pragma unroll
      for (int j = 0; j < 4; ++j) {
        int gn = n0 + wn + j*16 + r16;
        float bb = bias[gn];
        #pragma unroll
        for (int r = 0; r < 4; ++r) {
          int gm = m0 + wm + i*16 + q4*4 + r;
          float val = acc[i][j][r] + bb;
          if (flags & 1) val = fmaxf(val, 0.f);
          size_t co = (size_t)gm * N + gn;
          __bf16 hv = (__bf16)val;
          Ch[co] = hv;
          Cl[co] = (__bf16)(val - (float)hv);
        }
      }
  }
}

// ---------------------------------------------------------------------------
// attention: 1-D grid 8192, decoded so batch b == XCD (lin&7): K/V of a batch
// stay L2-resident on one XCD. Heavy q-tiles first within each XCD.
// phase 1: scores via MFMA (split-3), K frags direct global->reg, depth-1
//          prefetch.
// phase 2: softmax + exact top-5 re-softmax, 4 rows lockstep; final
//          normalized p written to Ssc in fp32; survivor masks via
//          ballot(p>0) -- survivor set is exactly {p_final > 0}.
// phase 3: SPARSE gather-PV: per row, iterate ~5 survivor keys, gather
//          V[b][key][hd*64+lane] (natural layout, coalesced), fp32 FMA.
//          No MFMA, no P conversion, no barrier (rows are wave-private).
// ---------------------------------------------------------------------------
__global__ __launch_bounds__(256, 4)
void attn_kernel(const __bf16* __restrict__ qh, const __bf16* __restrict__ ql,
                 const __bf16* __restrict__ vh, const __bf16* __restrict__ vl,
                 __bf16* __restrict__ oh, __bf16* __restrict__ ol)
{
  constexpr int LSS = 516;                       // fp32 row stride (pad 4)
  __shared__ float Ssc[16*LSS];                  // 33 KB scores; final p after phase 2
  const int lin = blockIdx.x;
  const int xcd = lin & 7;
  const int ord = lin >> 3;                      // 0..1023 per xcd
  const int qt  = 31 - (ord & 31);               // heavy tiles first
  const int bh  = ord >> 5;                      // 0..31
  const int hd  = bh & 7;
  const int b   = ((bh >> 3) << 3) | xcd;        // b mod 8 == xcd
  const int t = threadIdx.x, w = t >> 6, lane = t & 63;
  const int q4 = lane >> 4, r16 = lane & 15;
  const int nkt = (qt >> 2) + 1;                 // 64-key tiles (causal)

  // Q fragments (A operand): rows qt*16+[0,16), cols hd*64+[0,64)
  bfx8 qf[2][2];
  {
    size_t base = ((size_t)(b*S_ + qt*16 + r16)) * D_ + hd*64;
    #pragma unroll
    for (int ks = 0; ks < 2; ++ks) {
      qf[ks][0] = *(const bfx8*)&qh[base + ks*32 + q4*8];
      qf[ks][1] = *(const bfx8*)&ql[base + ks*32 + q4*8];
    }
  }

  // fragment registers: current (c*) and prefetch (n*)
  bfx8 ch0, ch1, cl0, cl1, nh0, nh1, nl0, nl1;

  // ---- phase 1: scores; K B-frag row = kt*64 + w*16 + r16, col chunk q4*8 ----
  const size_t kstep = (size_t)64 * D_;
  const size_t kb0 = ((size_t)(b*S_ + w*16 + r16)) * D_ + hd*64 + q4*8;
  ch0 = *(const bfx8*)&qh[kb0];
  ch1 = *(const bfx8*)&qh[kb0 + 32];
  cl0 = *(const bfx8*)&ql[kb0];
  cl1 = *(const bfx8*)&ql[kb0 + 32];
  for (int kt = 0; kt < nkt; ++kt) {
    const bool more = (kt + 1 < nkt);
    if (more) {
      size_t nb = kb0 + (size_t)(kt + 1) * kstep;
      nh0 = *(const bfx8*)&qh[nb];
      nh1 = *(const bfx8*)&qh[nb + 32];
      nl0 = *(const bfx8*)&ql[nb];
      nl1 = *(const bfx8*)&ql[nb + 32];
    }
    floatx4 acc = (floatx4){0.f, 0.f, 0.f, 0.f};
    __builtin_amdgcn_s_setprio(1);
    acc = mfma_bf16(qf[0][0], ch0, acc);   // ks=0: h,l,h  then ks=1: h,l,h
    acc = mfma_bf16(qf[0][0], cl0, acc);
    acc = mfma_bf16(qf[0][1], ch0, acc);
    acc = mfma_bf16(qf[1][0], ch1, acc);
    acc = mfma_bf16(qf[1][0], cl1, acc);
    acc = mfma_bf16(qf[1][1], ch1, acc);
    __builtin_amdgcn_s_setprio(0);
    int gcol = kt*64 + w*16 + r16;
    #pragma unroll
    for (int r = 0; r < 4; ++r) {
      int lrow = q4*4 + r;
      int grow = qt*16 + lrow;
      float sc = acc[r] * 0.125f;          // / sqrt(64)
      if (gcol >= grow) sc = -1e32f;       // strictly causal (tril k=-1)
      Ssc[lrow*LSS + gcol] = sc;
    }
    if (more) { ch0 = nh0; ch1 = nh1; cl0 = nl0; cl1 = nl1; }
  }
  __syncthreads();                         // phase-1 Ssc writes -> phase-2 reads

  // ---- phase 2: softmax + exact top-5 re-softmax; wave w owns rows w*4..+3,
  // 4 rows in LOCKSTEP.
  {
    float p[4][8], mx[4], sm[4];
    #pragma unroll
    for (int rr = 0; rr < 4; ++rr) {
      const int lrow = w*4 + rr;
      float m = -3.0e38f;
      #pragma unroll
      for (int j = 0; j < 8; ++j) {
        p[rr][j] = (j < nkt) ? Ssc[lrow*LSS + j*64 + lane] : -1e32f;
        m = fmaxf(m, p[rr][j]);
      }
      mx[rr] = m;
    }
    #pragma unroll
    for (int d = 32; d > 0; d >>= 1) {
      #pragma unroll
      for (int rr = 0; rr < 4; ++rr) mx[rr] = fmaxf(mx[rr], __shfl_xor(mx[rr], d));
    }
    #pragma unroll
    for (int rr = 0; rr < 4; ++rr) {
      float s = 0.f;
      #pragma unroll
      for (int j = 0; j < 8; ++j) { p[rr][j] = __expf(p[rr][j] - mx[rr]); s += p[rr][j]; }
      sm[rr] = s;
    }
    #pragma unroll
    for (int d = 32; d > 0; d >>= 1) {
      #pragma unroll
      for (int rr = 0; rr < 4; ++rr) sm[rr] += __shfl_xor(sm[rr], d);
    }
    #pragma unroll
    for (int rr = 0; rr < 4; ++rr) {
      float inv = 1.0f / sm[rr];
      #pragma unroll
      for (int j = 0; j < 8; ++j) p[rr][j] *= inv;   // masked j: exp -> 0
    }

    // exact 5th order statistic (with duplicates, matching lax.top_k):
    // 5 sequential rounds, the wave's 4 rows interleaved per round.
    unsigned rm[4] = {0u, 0u, 0u, 0u};
    float pmax[4], thr[4];
    for (int it = 0; it < 5; ++it) {
      float loc[4]; int locj[4];
      #pragma unroll
      for (int rr = 0; rr < 4; ++rr) {
        loc[rr] = -1.f; locj[rr] = 0;
        #pragma unroll
        for (int j = 0; j < 8; ++j)
          if (!((rm[rr] >> j) & 1u) && p[rr][j] > loc[rr]) { loc[rr] = p[rr][j]; locj[rr] = j; }
      }
      float wm4[4] = {loc[0], loc[1], loc[2], loc[3]};
      #pragma unroll
      for (int d = 32; d > 0; d >>= 1) {
        #pragma unroll
        for (int rr = 0; rr < 4; ++rr) wm4[rr] = fmaxf(wm4[rr], __shfl_xor(wm4[rr], d));
      }
      #pragma unroll
      for (int rr = 0; rr < 4; ++rr) {
        if (it == 0) pmax[rr] = wm4[rr];
        thr[rr] = wm4[rr];
        unsigned long long ball = __ballot(loc[rr] == wm4[rr]);
        int first = (int)__builtin_ctzll(ball);          // remove one instance
        if (lane == first) rm[rr] |= 1u << locj[rr];
      }
    }

    // sparse re-softmax (grow > 5 rows only; grow is wave-uniform per rr).
    float s2[4];
    #pragma unroll
    for (int rr = 0; rr < 4; ++rr) {
      const int grow = qt*16 + w*4 + rr;               // wave-uniform
      if (grow > 5) {
        float s = 0.f;
        #pragma unroll
        for (int j = 0; j < 8; ++j) {
          float vv = (p[rr][j] - thr[rr] >= 0.f) ? __expf(p[rr][j] - pmax[rr]) : 0.f;
          p[rr][j] = vv; s += vv;
        }
        s2[rr] = s;
      } else {
        s2[rr] = 1.f;                                  // unused; keeps inv finite
      }
    }
    #pragma unroll
    for (int d = 32; d > 0; d >>= 1) {
      #pragma unroll
      for (int rr = 0; rr < 4; ++rr) s2[rr] += __shfl_xor(s2[rr], d);
    }

    // ---- finalize + SPARSE gather-PV, per row (wave-private; no barrier) ----
    const __bf16* vbh = vh + (size_t)b*S_*D_ + hd*64 + lane;   // V[b][key][hd*64+lane]
    const __bf16* vbl = vl + (size_t)b*S_*D_ + hd*64 + lane;
    #pragma unroll
    for (int rr = 0; rr < 4; ++rr) {
      const int lrow = w*4 + rr, grow = qt*16 + lrow;  // wave-uniform
      const float inv2 = 1.0f / s2[rr];
      float* Prow = &Ssc[lrow*LSS];
      // final normalized p (fp32) -> Ssc; survivor masks via ballot(p>0)
      unsigned long long msk[8];
      #pragma unroll
      for (int j = 0; j < 8; ++j) {
        float f = (grow == 0) ? 0.f
                : (grow <= 5) ? p[rr][j]
                : p[rr][j] * inv2;
        Prow[j*64 + lane] = f;
        msk[j] = __ballot(f > 0.f);
      }
      // gather: O[grow][hd*64+lane] = sum over survivors f_key * V[b][key][..]
      float oacc = 0.f;
      #pragma unroll
      for (int j = 0; j < 8; ++j) {
        unsigned long long m = msk[j];
        while (m) {
          int kk = (int)__builtin_ctzll(m); m &= m - 1;
          int key = j*64 + kk;
          float pv = Prow[j*64 + kk];                  // LDS broadcast read
          size_t vo = (size_t)key * D_;
          float vv = (float)vbh[vo] + (float)vbl[vo];  // coalesced 128B rows
          oacc = fmaf(pv, vv, oacc);
        }
      }
      size_t off = ((size_t)(b*S_ + grow)) * D_ + hd*64 + lane;
      __bf16 hv = (__bf16)oacc;
      oh[off] = hv;
      ol[off] = (__bf16)(oacc - (float)hv);
    }
  }
}

// ---------------------------------------------------------------------------
// residual + LayerNorm (fp32): x = LN(xh+xl + th+tl); writes bf16 hi/lo pair
// and (if fout) the exact fp32 result. 1 wave/row, 4 rows/block.
// ---------------------------------------------------------------------------
__global__ void resid_ln_kernel(const __bf16* __restrict__ xhin, const __bf16* __restrict__ xlin,
                                const __bf16* __restrict__ thin, const __bf16* __restrict__ tlin,
                                const float* __restrict__ g, const float* __restrict__ bb,
                                __bf16* __restrict__ xh, __bf16* __restrict__ xl,
                                float* __restrict__ fout)
{
  int row = blockIdx.x * 4 + (threadIdx.x >> 6);
  int lane = threadIdx.x & 63;
  size_t base = (size_t)row * D_ + lane * 8;
  bfx8 h8 = *(const bfx8*)(xhin + base);
  bfx8 l8 = *(const bfx8*)(xlin + base);
  bfx8 th8 = *(const bfx8*)(thin + base);
  bfx8 tl8 = *(const bfx8*)(tlin + base);
  float v[8];
  #pragma unroll
  for (int j = 0; j < 8; ++j)
    v[j] = ((float)h8[j] + (float)l8[j]) + ((float)th8[j] + (float)tl8[j]);
  float s = 0.f;
  #pragma unroll
  for (int j = 0; j < 8; ++j) s += v[j];
  s = wave_sum(s);
  float mean = s * (1.0f/512.0f);
  float var = 0.f;
  #pragma unroll
  for (int j = 0; j < 8; ++j) { float d = v[j] - mean; var += d*d; }
  var = wave_sum(var) * (1.0f/512.0f);
  float rs = 1.0f / sqrtf(var + 1e-5f);
  float4 g0 = *(const float4*)(g + lane*8);
  float4 g1 = *(const float4*)(g + lane*8 + 4);
  float4 b0 = *(const float4*)(bb + lane*8);
  float4 b1 = *(const float4*)(bb + lane*8 + 4);
  float gg[8]  = {g0.x,g0.y,g0.z,g0.w,g1.x,g1.y,g1.z,g1.w};
  float bbv[8] = {b0.x,b0.y,b0.z,b0.w,b1.x,b1.y,b1.z,b1.w};
  float o[8];
  #pragma unroll
  for (int j = 0; j < 8; ++j) o[j] = (v[j] - mean) * rs * gg[j] + bbv[j];
  bfx8 hv8, lv8;
  #pragma unroll
  for (int j = 0; j < 8; ++j) {
    __bf16 hv = (__bf16)o[j];
    hv8[j] = hv;
    lv8[j] = (__bf16)(o[j] - (float)hv);
  }
  *(bfx8*)(xh + base) = hv8;
  *(bfx8*)(xl + base) = lv8;
  if (fout) {
    *(float4*)(fout + base)     = make_float4(o[0],o[1],o[2],o[3]);
    *(float4*)(fout + base + 4) = make_float4(o[4],o[5],o[6],o[7]);
  }
}

// ---------------------------------------------------------------------------
extern "C" void kernel_launch(void* const* d_in, const int* in_sizes, int n_in,
                              void* d_out, int out_size, void* d_ws, size_t ws_size,
                              hipStream_t stream)
{
  const float* qe   = (const float*)d_in[0];
  const float* ie   = (const float*)d_in[1];
  const float* pos  = (const float*)d_in[2];
  const float* Wk   = (const float*)d_in[3];
  const float* bk   = (const float*)d_in[4];
  const float* Wv   = (const float*)d_in[5];
  const float* bv   = (const float*)d_in[6];
  const float* Wo   = (const float*)d_in[7];
  const float* bo   = (const float*)d_in[8];
  const float* ln1g = (const float*)d_in[9];
  const float* ln1b = (const float*)d_in[10];
  const float* W1   = (const float*)d_in[11];
  const float* b1   = (const float*)d_in[12];
  const float* W2   = (const float*)d_in[13];
  const float* b2   = (const float*)d_in[14];
  const float* ln2g = (const float*)d_in[15];
  const float* ln2b = (const float*)d_in[16];

  char* wsp = (char*)d_ws;
  size_t off = 0;
  auto alloc = [&](size_t bytes) -> void* {
    void* p = wsp + off;
    off += (bytes + 255) & ~(size_t)255;
    return p;
  };
  const size_t NB = (size_t)BS_ * D_ * sizeof(__bf16);   // 16 MB per bf16 activation
  __bf16* xh  = (__bf16*)alloc(NB);
  __bf16* xl  = (__bf16*)alloc(NB);
  // q region aliases t (attn-out-proj / FFN2 result): q dead once out-proj runs
  char*   qt_ = (char*)  alloc(2*NB);
  __bf16* qhb = (__bf16*)qt_;
  __bf16* qlb = (__bf16*)(qt_ + NB);
  __bf16* thb = (__bf16*)qt_;
  __bf16* tlb = (__bf16*)(qt_ + NB);
  __bf16* vhb = (__bf16*)alloc(NB);       // V hi ([b][s][d], natural layout)
  __bf16* vlb = (__bf16*)alloc(NB);       // V lo
  // o region (2*NB) aliases chunked-FFN hidden-hi (M=8192: 8192*2048*2B = 2*NB)
  char*   oh_ = (char*) alloc(2*NB);
  __bf16* ohb = (__bf16*)oh_;
  __bf16* olb = (__bf16*)(oh_ + NB);
  __bf16* hhb = (__bf16*)oh_;             // chunked-path hidden-hi alias
  __bf16* hlb = (__bf16*)alloc(2*NB);     // chunked-path hidden-lo, 32 MB
  const size_t LW = 3*(size_t)D_*D_ + 2*(size_t)D_*DFF_;   // elems / layer
  __bf16* wth = (__bf16*)alloc(2*LW*sizeof(__bf16));
  __bf16* wtl = (__bf16*)alloc(2*LW*sizeof(__bf16));
  // y = ie + pos as bf16 hi/lo (used only if ws fits)
  __bf16* yh = (__bf16*)alloc(NB);
  __bf16* yl = (__bf16*)alloc(NB);
  const bool have_y = (off <= ws_size);
  // full-size FFN hidden buffers (M=16384): 64 MB hi + 64 MB lo.
  // Enables un-chunked FFN2 (grid 512 = 2 blocks/CU vs chunked 256 = 1/CU).
  const size_t HB = (size_t)BS_ * DFF_ * sizeof(__bf16);  // 64 MB
  __bf16* hhf = (__bf16*)alloc(HB);
  __bf16* hlf = (__bf16*)alloc(HB);
  const bool have_ffn = (off <= ws_size);
  float*  xout = (float*)d_out;
  // ws usage: ~184 MB base, ~216 MB +y, ~345 MB +full-FFN

  const size_t OK = 0, OV = (size_t)D_*D_, OO = 2*(size_t)D_*D_;
  const size_t O1 = 3*(size_t)D_*D_, O2 = 3*(size_t)D_*D_ + (size_t)D_*DFF_;

  // weight transposes + splits (recomputed each call; graph-capture safe)
  for (int l = 0; l < L_; ++l) {
    size_t base = (size_t)l * LW;
    transpose_split_kernel<<<dim3(16,16), 256, 0, stream>>>(Wk + (size_t)l*D_*D_,   wth+base+OK, wtl+base+OK, D_,  D_);
    transpose_split_kernel<<<dim3(16,16), 256, 0, stream>>>(Wv + (size_t)l*D_*D_,   wth+base+OV, wtl+base+OV, D_,  D_);
    transpose_split_kernel<<<dim3(16,16), 256, 0, stream>>>(Wo + (size_t)l*D_*D_,   wth+base+OO, wtl+base+OO, D_,  D_);
    transpose_split_kernel<<<dim3(64,16), 256, 0, stream>>>(W1 + (size_t)l*D_*DFF_, wth+base+O1, wtl+base+O1, D_,  DFF_);
    transpose_split_kernel<<<dim3(16,64), 256, 0, stream>>>(W2 + (size_t)l*DFF_*D_, wth+base+O2, wtl+base+O2, DFF_, D_);
  }

  init_x_kernel<<<4096, 256, 0, stream>>>(qe, pos, xh, xl);
  if (have_y)
    init_x_kernel<<<4096, 256, 0, stream>>>(ie, pos, yh, yl);

  for (int l = 0; l < L_; ++l) {
    size_t base = (size_t)l * LW;
    // q = k = x @ Wk + bk (kq_same), bf16 hi/lo out
    gemm_split3_kernel<<<dim3(4,128), 256, 0, stream>>>(xh, xl, nullptr, nullptr,
        wth+base+OK, wtl+base+OK, bk + (size_t)l*D_, qhb, qlb, BS_, D_, D_, 0);
    // v = (ie + pos) @ Wv + bv, natural [b][s][d] layout
    if (have_y)   // fast DMA path: y precomputed
      gemm_split3_kernel<<<dim3(4,128), 256, 0, stream>>>(yh, yl, nullptr, nullptr,
          wth+base+OV, wtl+base+OV, bv + (size_t)l*D_, vhb, vlb, BS_, D_, D_, 0);
    else          // fallback: fused fp32 y staging
      gemm_split3_kernel<<<dim3(4,128), 256, 0, stream>>>(nullptr, nullptr, ie, pos,
          wth+base+OV, wtl+base+OV, bv + (size_t)l*D_, vhb, vlb, BS_, D_, D_, 4);
    // sparse attention (1-D grid, XCD-affine decode inside)
    attn_kernel<<<dim3(32*H_*B_), 256, 0, stream>>>(qhb, qlb, vhb, vlb, ohb, olb);
    // out-proj -> t (hi/lo; overwrites q region, q is dead)
    gemm_split3_kernel<<<dim3(4,128), 256, 0, stream>>>(ohb, olb, nullptr, nullptr,
        wth+base+OO, wtl+base+OO, bo + (size_t)l*D_, thb, tlb, BS_, D_, D_, 0);
    // x = LN1(x + t)
    resid_ln_kernel<<<BS_/4, 256, 0, stream>>>(xh, xl, thb, tlb,
        ln1g + (size_t)l*D_, ln1b + (size_t)l*D_, xh, xl, nullptr);
    if (have_ffn) {
      // un-chunked FFN: FFN1 grid 2048 blocks, FFN2 grid 512 blocks (2/CU)
      gemm_split3_kernel<<<dim3(16,128), 256, 0, stream>>>(xh, xl, nullptr, nullptr,
          wth+base+O1, wtl+base+O1, b1 + (size_t)l*DFF_, hhf, hlf, BS_, DFF_, D_, 1);
      gemm_split3_kernel<<<dim3(4,128), 256, 0, stream>>>(hhf, hlf, nullptr, nullptr,
          wth+base+O2, wtl+base+O2, b2 + (size_t)l*D_, thb, tlb, BS_, D_, DFF_, 0);
    } else {
      // chunked fallback (hidden-hi aliases o region, out -> t region)
      for (int ch = 0; ch < 2; ++ch) {
        size_t ao = (size_t)ch*8192*D_;
        gemm_split3_kernel<<<dim3(16,64), 256, 0, stream>>>(xh + ao, xl + ao, nullptr, nullptr,
            wth+base+O1, wtl+base+O1, b1 + (size_t)l*DFF_, hhb, hlb, 8192, DFF_, D_, 1);
        gemm_split3_kernel<<<dim3(4,64), 256, 0, stream>>>(hhb, hlb, nullptr, nullptr,
            wth+base+O2, wtl+base+O2, b2 + (size_t)l*D_, thb + ao, tlb + ao, 8192, D_, DFF_, 0);
      }
    }
    // x = LN2(x + t); final layer writes fp32 straight to d_out
    resid_ln_kernel<<<BS_/4, 256, 0, stream>>>(xh, xl, thb, tlb,
        ln2g + (size_t)l*D_, ln2b + (size_t)l*D_, xh, xl,
        (l == L_-1) ? xout : nullptr);
  }
}